// Round 3
// baseline (24215.672 us; speedup 1.0000x reference)
//
#include <hip/hip_runtime.h>
#include <hip/hip_fp16.h>

// Problem constants: B=512, S=128, D=2, H=512, 4H=2048
#define PB 512
#define PS 128
#define PD 2
#define PH 512
#define P4H 2048

typedef unsigned int u32;
typedef unsigned short u16;
typedef unsigned char u8;

__device__ __forceinline__ float fast_sigmoid(float x) {
    return __fdividef(1.0f, 1.0f + __expf(-x));
}

__device__ __forceinline__ float fast_tanh(float x) {
    float ax = fabsf(x);
    float e = __expf(-2.0f * ax);
    float r = __fdividef(1.0f - e, 1.0f + e);
    return x < 0.0f ? -r : r;
}

// ---------------------------------------------------------------------------
// Storage codecs for the two large [S,B,H] arrays (enc_out, W1e).
// ---------------------------------------------------------------------------
struct CF32 {
    using T = float;
    static __device__ __forceinline__ float dec(T v) { return v; }
    static __device__ __forceinline__ T enc(float v) { return v; }
    static __device__ __forceinline__ void dec4(const T* p, float* o) {
        float4 v = *(const float4*)p; o[0]=v.x; o[1]=v.y; o[2]=v.z; o[3]=v.w;
    }
};
struct CBF16 {
    using T = u16;
    static __device__ __forceinline__ float dec(T v) {
        return __uint_as_float((u32)v << 16);
    }
    static __device__ __forceinline__ T enc(float v) {
        u32 u = __float_as_uint(v);
        return (T)((u + 0x7FFFu + ((u >> 16) & 1u)) >> 16);   // RNE
    }
    static __device__ __forceinline__ void dec4(const T* p, float* o) {
        uint2 v = *(const uint2*)p;
        o[0] = __uint_as_float(v.x << 16);
        o[1] = __uint_as_float(v.x & 0xFFFF0000u);
        o[2] = __uint_as_float(v.y << 16);
        o[3] = __uint_as_float(v.y & 0xFFFF0000u);
    }
};
struct CFP8 {  // e5m2 via fp16 truncation (no format-API dependence)
    using T = u8;
    union HU { __half h; u16 u; };
    static __device__ __forceinline__ float dec(T v) {
        HU hu; hu.u = (u16)v << 8;
        return __half2float(hu.h);
    }
    static __device__ __forceinline__ T enc(float v) {
        HU hu; hu.h = __float2half(v);
        return (T)((hu.u + 0x80u) >> 8);   // round to nearest (carry-safe for our range)
    }
    static __device__ __forceinline__ void dec4(const T* p, float* o) {
        u32 v = *(const u32*)p;
        o[0] = dec((T)(v & 0xFF));
        o[1] = dec((T)((v >> 8) & 0xFF));
        o[2] = dec((T)((v >> 16) & 0xFF));
        o[3] = dec((T)(v >> 24));
    }
};

// ---------------------------------------------------------------------------
// GEMM-NT: C[m,n] = sum_k A[m,k]*B[n,k] (+ bias[n]); A typed by CA, C by CO.
// B (weights) always fp32.
// ---------------------------------------------------------------------------
template<class CA, class CO, int BM, int BN, int BK, int TM, int TN>
__global__ __launch_bounds__(256) void gemm_nt(
    const typename CA::T* __restrict__ A, const float* __restrict__ Bm,
    const float* __restrict__ bias, typename CO::T* __restrict__ C,
    int M, int N, int K)
{
    __shared__ float As[BK][BM];
    __shared__ float Bs[BK][BN];
    constexpr int TCOLS = BN / TN;
    constexpr int TROWS = BM / TM;
    static_assert(TCOLS * TROWS == 256, "thread tiling");
    const int tid = threadIdx.x;
    const int tc = tid % TCOLS;
    const int tr = tid / TCOLS;
    const int bm = blockIdx.y * BM;
    const int bn = blockIdx.x * BN;
    constexpr int AF4 = BM * BK / 4;
    constexpr int BF4 = BN * BK / 4;
    constexpr int KQ  = BK / 4;

    float acc[TM][TN];
    #pragma unroll
    for (int m = 0; m < TM; ++m)
        #pragma unroll
        for (int n = 0; n < TN; ++n) acc[m][n] = 0.0f;

    for (int k0 = 0; k0 < K; k0 += BK) {
        #pragma unroll
        for (int i = tid; i < AF4; i += 256) {
            int r = i / KQ, kq = i % KQ;
            float v4[4];
            CA::dec4(A + (size_t)(bm + r) * K + k0 + kq * 4, v4);
            As[kq*4+0][r] = v4[0]; As[kq*4+1][r] = v4[1];
            As[kq*4+2][r] = v4[2]; As[kq*4+3][r] = v4[3];
        }
        #pragma unroll
        for (int i = tid; i < BF4; i += 256) {
            int r = i / KQ, kq = i % KQ;
            const float4 v = *(const float4*)(Bm + (size_t)(bn + r) * K + k0 + kq * 4);
            Bs[kq*4+0][r] = v.x; Bs[kq*4+1][r] = v.y;
            Bs[kq*4+2][r] = v.z; Bs[kq*4+3][r] = v.w;
        }
        __syncthreads();
        #pragma unroll
        for (int k = 0; k < BK; ++k) {
            float av[TM], bv[TN];
            #pragma unroll
            for (int m = 0; m < TM; ++m) av[m] = As[k][tr * TM + m];
            #pragma unroll
            for (int n = 0; n < TN; ++n) bv[n] = Bs[k][tc * TN + n];
            #pragma unroll
            for (int m = 0; m < TM; ++m)
                #pragma unroll
                for (int n = 0; n < TN; ++n)
                    acc[m][n] = fmaf(av[m], bv[n], acc[m][n]);
        }
        __syncthreads();
    }

    #pragma unroll
    for (int m = 0; m < TM; ++m) {
        int row = bm + tr * TM + m;
        #pragma unroll
        for (int n = 0; n < TN; ++n) {
            int col = bn + tc * TN + n;
            float v = acc[m][n];
            if (bias) v += bias[col];
            C[(size_t)row * N + col] = CO::enc(v);
        }
    }
}

// ---------------------------------------------------------------------------
// LSTM pointwise cell. `extra` (typed by CE) gets a copy of the new h.
// ---------------------------------------------------------------------------
template<class CE>
__global__ __launch_bounds__(256) void lstm_cell(
    const float* __restrict__ z,
    const float* __restrict__ x, int x_stride,
    const float* __restrict__ Wih,
    const float* __restrict__ bih, const float* __restrict__ bhh,
    float* __restrict__ c, float* __restrict__ h,
    typename CE::T* __restrict__ extra, int extra_stride)
{
    int idx = blockIdx.x * 256 + threadIdx.x;     // [0, B*H)
    int b = idx >> 9, j = idx & (PH - 1);
    float x0 = x[b * x_stride];
    float x1 = x[b * x_stride + 1];
    const float* zr = z + (size_t)b * P4H;
    float zi = zr[j]        + bih[j]        + bhh[j]        + x0 * Wih[2*j]          + x1 * Wih[2*j+1];
    float zf = zr[j + PH]   + bih[j + PH]   + bhh[j + PH]   + x0 * Wih[2*(j+PH)]     + x1 * Wih[2*(j+PH)+1];
    float zg = zr[j + 2*PH] + bih[j + 2*PH] + bhh[j + 2*PH] + x0 * Wih[2*(j+2*PH)]   + x1 * Wih[2*(j+2*PH)+1];
    float zo = zr[j + 3*PH] + bih[j + 3*PH] + bhh[j + 3*PH] + x0 * Wih[2*(j+3*PH)]   + x1 * Wih[2*(j+3*PH)+1];
    float cv = fast_sigmoid(zf) * c[idx] + fast_sigmoid(zi) * fast_tanh(zg);
    float hv = fast_sigmoid(zo) * fast_tanh(cv);
    c[idx] = cv;
    h[idx] = hv;
    if (extra) extra[(size_t)b * extra_stride + j] = CE::enc(hv);
}

// ---------------------------------------------------------------------------
// u[s,b] = v_w . tanh(W1e[s,b,:] + q[b,:]) + v_b  -> u_t[b,s]
// One 64-lane wave per (s,b) row; 8 elems per lane.
// ---------------------------------------------------------------------------
template<class C>
__global__ __launch_bounds__(256) void u_pass(
    const typename C::T* __restrict__ W1e, const float* __restrict__ q,
    const float* __restrict__ v_w, const float* __restrict__ v_b,
    float* __restrict__ u_t)
{
    int row = blockIdx.x * 4 + (threadIdx.x >> 6);  // row = s*B + b
    int lane = threadIdx.x & 63;
    int s = row >> 9;
    int b = row & (PB - 1);
    const typename C::T* wr = W1e + (size_t)row * PH + lane * 8;
    const float* qr = q + (size_t)b * PH + lane * 8;
    const float* vr = v_w + lane * 8;
    float w8[8], q8[8], v8[8];
    C::dec4(wr, w8); C::dec4(wr + 4, w8 + 4);
    CF32::dec4(qr, q8); CF32::dec4(qr + 4, q8 + 4);
    CF32::dec4(vr, v8); CF32::dec4(vr + 4, v8 + 4);
    float sum = 0.0f;
    #pragma unroll
    for (int i = 0; i < 8; ++i)
        sum += v8[i] * fast_tanh(w8[i] + q8[i]);
    #pragma unroll
    for (int off = 32; off; off >>= 1) sum += __shfl_xor(sum, off);
    if (lane == 0) u_t[b * PS + s] = sum + v_b[0];
}

// ---------------------------------------------------------------------------
// Softmax over S per batch row + argmax (first occurrence) + cur gather.
// ---------------------------------------------------------------------------
__global__ __launch_bounds__(256) void softmax_step(
    const float* __restrict__ u_t, const float* __restrict__ inp,
    float* __restrict__ a_buf, float* __restrict__ out,
    float* __restrict__ cur, int t)
{
    int b = blockIdx.x * 4 + (threadIdx.x >> 6);
    int lane = threadIdx.x & 63;
    float2 uv = *(const float2*)&u_t[b * PS + lane * 2];
    float m = fmaxf(uv.x, uv.y);
    int mi = (uv.y > uv.x) ? (lane * 2 + 1) : (lane * 2);
    #pragma unroll
    for (int off = 32; off; off >>= 1) {
        float om = __shfl_xor(m, off);
        int oi = __shfl_xor(mi, off);
        if (om > m || (om == m && oi < mi)) { m = om; mi = oi; }
    }
    float e0 = __expf(uv.x - m);
    float e1 = __expf(uv.y - m);
    float ssum = e0 + e1;
    #pragma unroll
    for (int off = 32; off; off >>= 1) ssum += __shfl_xor(ssum, off);
    float inv = __fdividef(1.0f, ssum);
    float2 av = make_float2(e0 * inv, e1 * inv);
    *(float2*)&a_buf[b * PS + lane * 2] = av;
    *(float2*)&out[(size_t)b * PS * PS + (size_t)t * PS + lane * 2] = av;
    if (lane == 0) {
        cur[b * 2]     = inp[(size_t)b * PS * PD + mi * PD];
        cur[b * 2 + 1] = inp[(size_t)b * PS * PD + mi * PD + 1];
    }
}

// ---------------------------------------------------------------------------
// ctx[b,h] = sum_s a[b,s] * enc_out[s,b,h]  -> catbuf[b, 0:H]
// ---------------------------------------------------------------------------
template<class C>
__global__ __launch_bounds__(256) void ctx_kernel(
    const typename C::T* __restrict__ enc_out, const float* __restrict__ a_buf,
    float* __restrict__ catbuf)
{
    int b = blockIdx.x;
    int hidx = threadIdx.x;
    const float* ab = a_buf + b * PS;
    const typename C::T* e = enc_out + (size_t)b * PH;
    float acc0 = 0.0f, acc1 = 0.0f;
    #pragma unroll 4
    for (int s = 0; s < PS; ++s) {
        float a = ab[s];
        const typename C::T* es = e + (size_t)s * PB * PH;
        acc0 = fmaf(a, C::dec(es[hidx]), acc0);
        acc1 = fmaf(a, C::dec(es[hidx + 256]), acc1);
    }
    catbuf[(size_t)b * (2 * PH) + hidx] = acc0;
    catbuf[(size_t)b * (2 * PH) + hidx + 256] = acc1;
}

__global__ __launch_bounds__(256) void init_kernel(
    float* __restrict__ h, float* __restrict__ c, float* __restrict__ cur)
{
    int i = blockIdx.x * 256 + threadIdx.x;
    if (i < PB * PH) { h[i] = 0.0f; c[i] = 0.0f; }
    if (i < PB * PD) cur[i] = -1.0f;
}

// ---------------------------------------------------------------------------

template<class C>
static void run_pipeline(void* const* d_in, float* out, void* d_ws, hipStream_t stream)
{
    const float* inp     = (const float*)d_in[0];
    const float* enc_Wih = (const float*)d_in[1];
    const float* enc_Whh = (const float*)d_in[2];
    const float* enc_bih = (const float*)d_in[3];
    const float* enc_bhh = (const float*)d_in[4];
    const float* dec_Wih = (const float*)d_in[5];
    const float* dec_Whh = (const float*)d_in[6];
    const float* dec_bih = (const float*)d_in[7];
    const float* dec_bhh = (const float*)d_in[8];
    const float* W1      = (const float*)d_in[9];
    const float* b1      = (const float*)d_in[10];
    const float* W2      = (const float*)d_in[11];
    const float* b2      = (const float*)d_in[12];
    const float* v_w     = (const float*)d_in[13];
    const float* v_b     = (const float*)d_in[14];
    const float* comb_W  = (const float*)d_in[15];
    const float* comb_b  = (const float*)d_in[16];

    using T = typename C::T;
    const size_t big = (size_t)PS * PB * PH;      // 33,554,432 elements

    char* p = (char*)d_ws;
    T* enc_out = (T*)p;  p += big * sizeof(T);
    T* W1e     = (T*)p;  p += big * sizeof(T);
    float* ws  = (float*)p;
    size_t off = 0;
    auto alloc = [&](size_t n) { float* q_ = ws + off; off += n; return q_; };
    float* z      = alloc((size_t)PB * P4H);
    float* h      = alloc((size_t)PB * PH);
    float* c      = alloc((size_t)PB * PH);
    float* h0     = alloc((size_t)PB * PH);
    float* q      = alloc((size_t)PB * PH);
    float* catbuf = alloc((size_t)PB * 2 * PH);
    float* u_t    = alloc((size_t)PB * PS);
    float* a_buf  = alloc((size_t)PB * PS);
    float* cur    = alloc((size_t)PB * PD);

    init_kernel<<<1024, 256, 0, stream>>>(h, c, cur);

    // -------- encoder --------
    for (int s = 0; s < PS; ++s) {
        gemm_nt<CF32, CF32, 64, 64, 32, 4, 4><<<dim3(P4H / 64, PB / 64), 256, 0, stream>>>(
            h, enc_Whh, nullptr, z, PB, P4H, PH);
        lstm_cell<C><<<1024, 256, 0, stream>>>(
            z, inp + s * PD, PS * PD, enc_Wih, enc_bih, enc_bhh,
            c, h, enc_out + (size_t)s * PB * PH, PH);
    }

    // -------- W1e = enc_out @ W1.T + b1 --------
    gemm_nt<C, C, 64, 64, 32, 4, 4><<<dim3(PH / 64, (PS * PB) / 64), 256, 0, stream>>>(
        enc_out, W1, b1, W1e, PS * PB, PH, PH);

    // -------- decoder --------
    for (int t = 0; t < PS; ++t) {
        gemm_nt<CF32, CF32, 64, 64, 32, 4, 4><<<dim3(P4H / 64, PB / 64), 256, 0, stream>>>(
            h, dec_Whh, nullptr, z, PB, P4H, PH);
        lstm_cell<CF32><<<1024, 256, 0, stream>>>(
            z, cur, PD, dec_Wih, dec_bih, dec_bhh,
            c, h0, catbuf + PH, 2 * PH);
        gemm_nt<CF32, CF32, 32, 32, 32, 2, 2><<<dim3(PH / 32, PB / 32), 256, 0, stream>>>(
            h0, W2, b2, q, PB, PH, PH);
        u_pass<C><<<(PS * PB) / 4, 256, 0, stream>>>(W1e, q, v_w, v_b, u_t);
        softmax_step<<<PB / 4, 256, 0, stream>>>(u_t, inp, a_buf, out, cur, t);
        ctx_kernel<C><<<PB, 256, 0, stream>>>(enc_out, a_buf, catbuf);
        gemm_nt<CF32, CF32, 32, 32, 32, 2, 2><<<dim3(PH / 32, PB / 32), 256, 0, stream>>>(
            catbuf, comb_W, comb_b, h, PB, PH, 2 * PH);
    }
}

extern "C" void kernel_launch(void* const* d_in, const int* in_sizes, int n_in,
                              void* d_out, int out_size, void* d_ws, size_t ws_size,
                              hipStream_t stream)
{
    float* out = (float*)d_out;
    const size_t big = (size_t)PS * PB * PH;
    const size_t small_bytes = ((size_t)PB * P4H + 4 * (size_t)PB * PH +
                                (size_t)PB * 2 * PH + 2 * (size_t)PB * PS +
                                (size_t)PB * PD) * sizeof(float);
    // Tier selection (ws_size is fixed across calls -> graph-consistent).
    if (ws_size >= 2 * big * sizeof(float) + small_bytes) {
        run_pipeline<CF32>(d_in, out, d_ws, stream);
    } else if (ws_size >= 2 * big * sizeof(u16) + small_bytes) {
        run_pipeline<CBF16>(d_in, out, d_ws, stream);
    } else if (ws_size >= 2 * big * sizeof(u8) + small_bytes) {
        run_pipeline<CFP8>(d_in, out, d_ws, stream);
    }
    // else: insufficient workspace — nothing safe to do.
}

// Round 4
// 13464.458 us; speedup vs baseline: 1.7985x; 1.7985x over previous
//
#include <hip/hip_runtime.h>

// Problem constants: B=512, S=128, D=2, H=512, 4H=2048
#define PB 512
#define PS 128
#define PD 2
#define PH 512
#define P4H 2048

typedef unsigned int u32;
typedef unsigned short u16;
typedef __attribute__((ext_vector_type(8))) short short8;
typedef __attribute__((ext_vector_type(4))) float f32x4;

__device__ __forceinline__ float fast_sigmoid(float x) {
    return __fdividef(1.0f, 1.0f + __expf(-x));
}
__device__ __forceinline__ float fast_tanh(float x) {
    float ax = fabsf(x);
    float e = __expf(-2.0f * ax);
    float r = __fdividef(1.0f - e, 1.0f + e);
    return x < 0.0f ? -r : r;
}

__device__ __forceinline__ float bf_dec_u(u16 v) { return __uint_as_float((u32)v << 16); }
__device__ __forceinline__ u16 bf_trunc(float v) { return (u16)(__float_as_uint(v) >> 16); }
__device__ __forceinline__ u16 bf_rne(float v) {
    u32 u = __float_as_uint(v);
    return (u16)((u + 0x7FFFu + ((u >> 16) & 1u)) >> 16);
}
// split: v ~= hi + lo, residual ~2^-17 relative
__device__ __forceinline__ void bf_split(float v, u16& hi, u16& lo) {
    hi = bf_trunc(v);
    lo = bf_rne(v - bf_dec_u(hi));
}

// ---------------------------------------------------------------------------
// Storage codecs (kept for fallback path + u_pass/ctx)
// ---------------------------------------------------------------------------
struct CF32 {
    using T = float;
    static __device__ __forceinline__ float dec(T v) { return v; }
    static __device__ __forceinline__ T enc(float v) { return v; }
    static __device__ __forceinline__ void dec4(const T* p, float* o) {
        float4 v = *(const float4*)p; o[0]=v.x; o[1]=v.y; o[2]=v.z; o[3]=v.w;
    }
};
struct CBF16 {
    using T = u16;
    static __device__ __forceinline__ float dec(T v) { return __uint_as_float((u32)v << 16); }
    static __device__ __forceinline__ T enc(float v) { return bf_rne(v); }
    static __device__ __forceinline__ void dec4(const T* p, float* o) {
        uint2 v = *(const uint2*)p;
        o[0] = __uint_as_float(v.x << 16);
        o[1] = __uint_as_float(v.x & 0xFFFF0000u);
        o[2] = __uint_as_float(v.y << 16);
        o[3] = __uint_as_float(v.y & 0xFFFF0000u);
    }
};

// ===========================================================================
// Prep kernels (run once per launch; deterministic, graph-safe)
// ===========================================================================
// Permute Whh rows to gate-interleaved order n' = 4j+g (orig n = g*512+j), split hi/lo.
__global__ __launch_bounds__(256) void prep_whh(
    const float* __restrict__ Whh, u16* __restrict__ hi, u16* __restrict__ lo)
{
    int np = blockIdx.x;                 // 0..2047
    int j = np >> 2, g = np & 3;
    const float* src = Whh + (size_t)(g * PH + j) * PH;
    for (int k = threadIdx.x; k < PH; k += 256) {
        u16 h_, l_;
        bf_split(src[k], h_, l_);
        hi[(size_t)np * PH + k] = h_;
        lo[(size_t)np * PH + k] = l_;
    }
}
// Generic row-major [N][K] fp32 -> hi/lo bf16 split.
__global__ __launch_bounds__(256) void prep_split(
    const float* __restrict__ W, u16* __restrict__ hi, u16* __restrict__ lo, int K)
{
    int n = blockIdx.x;
    const float* src = W + (size_t)n * K;
    for (int k = threadIdx.x; k < K; k += 256) {
        u16 h_, l_;
        bf_split(src[k], h_, l_);
        hi[(size_t)n * K + k] = h_;
        lo[(size_t)n * K + k] = l_;
    }
}
// Permuted Wih [n'][2] fp32 and bsum[n'] = bih+bhh.
__global__ __launch_bounds__(256) void prep_small(
    const float* __restrict__ Wih, const float* __restrict__ bih,
    const float* __restrict__ bhh, float* __restrict__ wihp, float* __restrict__ bs)
{
    int np = blockIdx.x * 256 + threadIdx.x;
    if (np >= P4H) return;
    int j = np >> 2, g = np & 3;
    int n = g * PH + j;
    wihp[np * 2]     = Wih[(size_t)n * PD];
    wihp[np * 2 + 1] = Wih[(size_t)n * PD + 1];
    bs[np] = bih[n] + bhh[n];
}

// ===========================================================================
// Fused LSTM step: z^T = Whh_perm @ h^T via split-bf16 MFMA, cell in epilogue.
// MFMA orientation: A-op = Whh_perm rows (M-dim = n'), B-op = h rows (N-dim = b).
// C lane layout (16x16x32): col(b) = lane&15, rows(n') = (lane>>4)*4 + reg
//  -> each lane's 4 regs are gates i,f,g,o of one (b, j). Cell is lane-local.
// EXTRA_MODE: 1 = also write bf16 copy of h (enc_out slice), 2 = write fp32
//             copy into catbuf right half (stride 1024, offset 512).
// ===========================================================================
template<int EXTRA_MODE>
__global__ __launch_bounds__(256) void lstm_fused(
    const u16* __restrict__ Whh_hi, const u16* __restrict__ Whh_lo,
    const float* __restrict__ wih_perm, const float* __restrict__ bsum,
    const float* __restrict__ x, int x_stride,
    const float* __restrict__ h_in,
    float* __restrict__ cT,            // [j][b] transposed cell state
    float* __restrict__ h_out,         // [b][j]
    void* __restrict__ extra)
{
    __shared__ u16 As_hi[64][72];
    __shared__ u16 As_lo[64][72];
    __shared__ u16 Bs_hi[64][72];
    __shared__ u16 Bs_lo[64][72];

    const int tid = threadIdx.x;
    const int bb = blockIdx.x * 64;     // b base
    const int bn = blockIdx.y * 64;     // n' base
    const int w = tid >> 6;
    const int wm = w >> 1, wn = w & 1;  // wm: n'-half, wn: b-half
    const int lane = tid & 63;
    const int l15 = lane & 15, lq = lane >> 4;

    f32x4 acc[2][2];
    #pragma unroll
    for (int i = 0; i < 2; ++i)
        #pragma unroll
        for (int j = 0; j < 2; ++j)
            acc[i][j] = (f32x4)0.0f;

    for (int k0 = 0; k0 < PH; k0 += 64) {
        // stage A: pre-split weights, 16B chunks (512 chunks)
        #pragma unroll
        for (int rep = 0; rep < 2; ++rep) {
            int chunk = tid + rep * 256;
            int row = chunk >> 3, kc = (chunk & 7) * 8;
            *(uint4*)&As_hi[row][kc] = *(const uint4*)&Whh_hi[(size_t)(bn + row) * PH + k0 + kc];
            *(uint4*)&As_lo[row][kc] = *(const uint4*)&Whh_lo[(size_t)(bn + row) * PH + k0 + kc];
        }
        // stage B: h fp32 -> split hi/lo (1024 chunks of 4 floats)
        #pragma unroll
        for (int rep = 0; rep < 4; ++rep) {
            int chunk = tid + rep * 256;
            int row = chunk >> 4, kc = (chunk & 15) * 4;
            float4 v = *(const float4*)&h_in[(size_t)(bb + row) * PH + k0 + kc];
            u16 h0_, l0_, h1_, l1_, h2_, l2_, h3_, l3_;
            bf_split(v.x, h0_, l0_); bf_split(v.y, h1_, l1_);
            bf_split(v.z, h2_, l2_); bf_split(v.w, h3_, l3_);
            *(uint2*)&Bs_hi[row][kc] = make_uint2((u32)h0_ | ((u32)h1_ << 16),
                                                  (u32)h2_ | ((u32)h3_ << 16));
            *(uint2*)&Bs_lo[row][kc] = make_uint2((u32)l0_ | ((u32)l1_ << 16),
                                                  (u32)l2_ | ((u32)l3_ << 16));
        }
        __syncthreads();
        #pragma unroll
        for (int ks = 0; ks < 2; ++ks) {
            int kk = ks * 32 + lq * 8;
            short8 ah[2], al[2], bh[2], bl[2];
            #pragma unroll
            for (int mf = 0; mf < 2; ++mf) {
                int r = wm * 32 + mf * 16 + l15;
                ah[mf] = *(const short8*)&As_hi[r][kk];
                al[mf] = *(const short8*)&As_lo[r][kk];
            }
            #pragma unroll
            for (int nf = 0; nf < 2; ++nf) {
                int r = wn * 32 + nf * 16 + l15;
                bh[nf] = *(const short8*)&Bs_hi[r][kk];
                bl[nf] = *(const short8*)&Bs_lo[r][kk];
            }
            #pragma unroll
            for (int mf = 0; mf < 2; ++mf)
                #pragma unroll
                for (int nf = 0; nf < 2; ++nf) {
                    acc[mf][nf] = __builtin_amdgcn_mfma_f32_16x16x32_bf16(ah[mf], bh[nf], acc[mf][nf], 0, 0, 0);
                    acc[mf][nf] = __builtin_amdgcn_mfma_f32_16x16x32_bf16(ah[mf], bl[nf], acc[mf][nf], 0, 0, 0);
                    acc[mf][nf] = __builtin_amdgcn_mfma_f32_16x16x32_bf16(al[mf], bh[nf], acc[mf][nf], 0, 0, 0);
                }
        }
        __syncthreads();
    }

    // Epilogue: lane-local LSTM cell; h transposed via LDS for coalesced store.
    float* Hs = (float*)&As_hi[0][0];   // 16 x 66 floats, fits in As_hi+As_lo region
    #pragma unroll
    for (int nf = 0; nf < 2; ++nf) {
        int b_loc = wn * 32 + nf * 16 + l15;
        int b = bb + b_loc;
        float x0 = x[b * x_stride];
        float x1 = x[b * x_stride + 1];
        #pragma unroll
        for (int mf = 0; mf < 2; ++mf) {
            int np_loc = wm * 32 + mf * 16 + lq * 4;
            int np = bn + np_loc;                    // multiple of 4; gates r=0..3
            float4 b4 = *(const float4*)&bsum[np];
            float4 wA = *(const float4*)&wih_perm[np * 2];
            float4 wB = *(const float4*)&wih_perm[np * 2 + 4];
            float zi = acc[mf][nf][0] + b4.x + x0 * wA.x + x1 * wA.y;
            float zf = acc[mf][nf][1] + b4.y + x0 * wA.z + x1 * wA.w;
            float zg = acc[mf][nf][2] + b4.z + x0 * wB.x + x1 * wB.y;
            float zo = acc[mf][nf][3] + b4.w + x0 * wB.z + x1 * wB.w;
            int jg = np >> 2;
            float cold = cT[(size_t)jg * PB + b];
            float cv = fast_sigmoid(zf) * cold + fast_sigmoid(zi) * fast_tanh(zg);
            float hv = fast_sigmoid(zo) * fast_tanh(cv);
            cT[(size_t)jg * PB + b] = cv;
            Hs[(np_loc >> 2) * 66 + b_loc] = hv;
        }
    }
    __syncthreads();
    {
        int b_loc = tid >> 2, jp = (tid & 3) * 4;
        int b = bb + b_loc;
        int jbase = bn >> 2;
        float4 hv4;
        hv4.x = Hs[(jp + 0) * 66 + b_loc];
        hv4.y = Hs[(jp + 1) * 66 + b_loc];
        hv4.z = Hs[(jp + 2) * 66 + b_loc];
        hv4.w = Hs[(jp + 3) * 66 + b_loc];
        *(float4*)&h_out[(size_t)b * PH + jbase + jp] = hv4;
        if (EXTRA_MODE == 1) {
            u16* e = (u16*)extra;
            *(uint2*)&e[(size_t)b * PH + jbase + jp] =
                make_uint2((u32)bf_rne(hv4.x) | ((u32)bf_rne(hv4.y) << 16),
                           (u32)bf_rne(hv4.z) | ((u32)bf_rne(hv4.w) << 16));
        } else if (EXTRA_MODE == 2) {
            float* e = (float*)extra;
            *(float4*)&e[(size_t)b * (2 * PH) + PH + jbase + jp] = hv4;
        }
    }
}

// ===========================================================================
// MFMA GEMM, weights-as-A orientation: out[m][n] = act[m,:] . W[n,:] + bias[n]
// A-op = pre-split W rows; B-op = act rows (fp32 split, or bf16 single).
// Lane holds 4 consecutive n for one m -> vectorized output store.
// ===========================================================================
template<int ACT_F32, int OUT_BF16>
__global__ __launch_bounds__(256) void gemm_wtA(
    const u16* __restrict__ Whi, const u16* __restrict__ Wlo,
    const void* __restrict__ act, const float* __restrict__ bias,
    void* __restrict__ out, int K, int ldo)
{
    __shared__ u16 As_hi[64][72];
    __shared__ u16 As_lo[64][72];
    __shared__ u16 Bs_hi[64][72];
    __shared__ u16 Bs_lo[64][72];

    const int tid = threadIdx.x;
    const int bm = blockIdx.x * 64;     // act-row base
    const int bn = blockIdx.y * 64;     // weight-row base
    const int w = tid >> 6;
    const int wm = w >> 1, wn = w & 1;
    const int lane = tid & 63;
    const int l15 = lane & 15, lq = lane >> 4;

    f32x4 acc[2][2];
    #pragma unroll
    for (int i = 0; i < 2; ++i)
        #pragma unroll
        for (int j = 0; j < 2; ++j)
            acc[i][j] = (f32x4)0.0f;

    for (int k0 = 0; k0 < K; k0 += 64) {
        #pragma unroll
        for (int rep = 0; rep < 2; ++rep) {
            int chunk = tid + rep * 256;
            int row = chunk >> 3, kc = (chunk & 7) * 8;
            *(uint4*)&As_hi[row][kc] = *(const uint4*)&Whi[(size_t)(bn + row) * K + k0 + kc];
            *(uint4*)&As_lo[row][kc] = *(const uint4*)&Wlo[(size_t)(bn + row) * K + k0 + kc];
        }
        if (ACT_F32) {
            const float* a = (const float*)act;
            #pragma unroll
            for (int rep = 0; rep < 4; ++rep) {
                int chunk = tid + rep * 256;
                int row = chunk >> 4, kc = (chunk & 15) * 4;
                float4 v = *(const float4*)&a[(size_t)(bm + row) * K + k0 + kc];
                u16 h0_, l0_, h1_, l1_, h2_, l2_, h3_, l3_;
                bf_split(v.x, h0_, l0_); bf_split(v.y, h1_, l1_);
                bf_split(v.z, h2_, l2_); bf_split(v.w, h3_, l3_);
                *(uint2*)&Bs_hi[row][kc] = make_uint2((u32)h0_ | ((u32)h1_ << 16),
                                                      (u32)h2_ | ((u32)h3_ << 16));
                *(uint2*)&Bs_lo[row][kc] = make_uint2((u32)l0_ | ((u32)l1_ << 16),
                                                      (u32)l2_ | ((u32)l3_ << 16));
            }
        } else {
            const u16* a = (const u16*)act;
            #pragma unroll
            for (int rep = 0; rep < 2; ++rep) {
                int chunk = tid + rep * 256;
                int row = chunk >> 3, kc = (chunk & 7) * 8;
                *(uint4*)&Bs_hi[row][kc] = *(const uint4*)&a[(size_t)(bm + row) * K + k0 + kc];
            }
        }
        __syncthreads();
        #pragma unroll
        for (int ks = 0; ks < 2; ++ks) {
            int kk = ks * 32 + lq * 8;
            short8 ah[2], al[2], bh[2], bl[2];
            #pragma unroll
            for (int mf = 0; mf < 2; ++mf) {
                int r = wm * 32 + mf * 16 + l15;
                ah[mf] = *(const short8*)&As_hi[r][kk];
                al[mf] = *(const short8*)&As_lo[r][kk];
            }
            #pragma unroll
            for (int nf = 0; nf < 2; ++nf) {
                int r = wn * 32 + nf * 16 + l15;
                bh[nf] = *(const short8*)&Bs_hi[r][kk];
                if (ACT_F32) bl[nf] = *(const short8*)&Bs_lo[r][kk];
            }
            #pragma unroll
            for (int mf = 0; mf < 2; ++mf)
                #pragma unroll
                for (int nf = 0; nf < 2; ++nf) {
                    acc[mf][nf] = __builtin_amdgcn_mfma_f32_16x16x32_bf16(ah[mf], bh[nf], acc[mf][nf], 0, 0, 0);
                    if (ACT_F32) {
                        acc[mf][nf] = __builtin_amdgcn_mfma_f32_16x16x32_bf16(ah[mf], bl[nf], acc[mf][nf], 0, 0, 0);
                        acc[mf][nf] = __builtin_amdgcn_mfma_f32_16x16x32_bf16(al[mf], bh[nf], acc[mf][nf], 0, 0, 0);
                    } else {
                        acc[mf][nf] = __builtin_amdgcn_mfma_f32_16x16x32_bf16(al[mf], bh[nf], acc[mf][nf], 0, 0, 0);
                    }
                }
        }
        __syncthreads();
    }

    #pragma unroll
    for (int nf = 0; nf < 2; ++nf) {
        int m = bm + wn * 32 + nf * 16 + l15;
        #pragma unroll
        for (int mf = 0; mf < 2; ++mf) {
            int n = bn + wm * 32 + mf * 16 + lq * 4;   // multiple of 4
            float4 b4 = bias ? *(const float4*)&bias[n] : make_float4(0.f, 0.f, 0.f, 0.f);
            float v0 = acc[mf][nf][0] + b4.x;
            float v1 = acc[mf][nf][1] + b4.y;
            float v2 = acc[mf][nf][2] + b4.z;
            float v3 = acc[mf][nf][3] + b4.w;
            if (OUT_BF16) {
                u16* o = (u16*)out;
                *(uint2*)&o[(size_t)m * ldo + n] =
                    make_uint2((u32)bf_rne(v0) | ((u32)bf_rne(v1) << 16),
                               (u32)bf_rne(v2) | ((u32)bf_rne(v3) << 16));
            } else {
                float* o = (float*)out;
                *(float4*)&o[(size_t)m * ldo + n] = make_float4(v0, v1, v2, v3);
            }
        }
    }
}

// ===========================================================================
// Unchanged small kernels (u_pass / softmax / ctx / init) + fallback path
// ===========================================================================
template<class C>
__global__ __launch_bounds__(256) void u_pass(
    const typename C::T* __restrict__ W1e, const float* __restrict__ q,
    const float* __restrict__ v_w, const float* __restrict__ v_b,
    float* __restrict__ u_t)
{
    int row = blockIdx.x * 4 + (threadIdx.x >> 6);  // row = s*B + b
    int lane = threadIdx.x & 63;
    int s = row >> 9;
    int b = row & (PB - 1);
    const typename C::T* wr = W1e + (size_t)row * PH + lane * 8;
    const float* qr = q + (size_t)b * PH + lane * 8;
    const float* vr = v_w + lane * 8;
    float w8[8], q8[8], v8[8];
    C::dec4(wr, w8); C::dec4(wr + 4, w8 + 4);
    CF32::dec4(qr, q8); CF32::dec4(qr + 4, q8 + 4);
    CF32::dec4(vr, v8); CF32::dec4(vr + 4, v8 + 4);
    float sum = 0.0f;
    #pragma unroll
    for (int i = 0; i < 8; ++i)
        sum += v8[i] * fast_tanh(w8[i] + q8[i]);
    #pragma unroll
    for (int off = 32; off; off >>= 1) sum += __shfl_xor(sum, off);
    if (lane == 0) u_t[b * PS + s] = sum + v_b[0];
}

__global__ __launch_bounds__(256) void softmax_step(
    const float* __restrict__ u_t, const float* __restrict__ inp,
    float* __restrict__ a_buf, float* __restrict__ out,
    float* __restrict__ cur, int t)
{
    int b = blockIdx.x * 4 + (threadIdx.x >> 6);
    int lane = threadIdx.x & 63;
    float2 uv = *(const float2*)&u_t[b * PS + lane * 2];
    float m = fmaxf(uv.x, uv.y);
    int mi = (uv.y > uv.x) ? (lane * 2 + 1) : (lane * 2);
    #pragma unroll
    for (int off = 32; off; off >>= 1) {
        float om = __shfl_xor(m, off);
        int oi = __shfl_xor(mi, off);
        if (om > m || (om == m && oi < mi)) { m = om; mi = oi; }
    }
    float e0 = __expf(uv.x - m);
    float e1 = __expf(uv.y - m);
    float ssum = e0 + e1;
    #pragma unroll
    for (int off = 32; off; off >>= 1) ssum += __shfl_xor(ssum, off);
    float inv = __fdividef(1.0f, ssum);
    float2 av = make_float2(e0 * inv, e1 * inv);
    *(float2*)&a_buf[b * PS + lane * 2] = av;
    *(float2*)&out[(size_t)b * PS * PS + (size_t)t * PS + lane * 2] = av;
    if (lane == 0) {
        cur[b * 2]     = inp[(size_t)b * PS * PD + mi * PD];
        cur[b * 2 + 1] = inp[(size_t)b * PS * PD + mi * PD + 1];
    }
}

template<class C>
__global__ __launch_bounds__(256) void ctx_kernel(
    const typename C::T* __restrict__ enc_out, const float* __restrict__ a_buf,
    float* __restrict__ catbuf)
{
    int b = blockIdx.x;
    int hidx = threadIdx.x;
    const float* ab = a_buf + b * PS;
    const typename C::T* e = enc_out + (size_t)b * PH;
    float acc0 = 0.0f, acc1 = 0.0f;
    #pragma unroll 4
    for (int s = 0; s < PS; ++s) {
        float a = ab[s];
        const typename C::T* es = e + (size_t)s * PB * PH;
        acc0 = fmaf(a, C::dec(es[hidx]), acc0);
        acc1 = fmaf(a, C::dec(es[hidx + 256]), acc1);
    }
    catbuf[(size_t)b * (2 * PH) + hidx] = acc0;
    catbuf[(size_t)b * (2 * PH) + hidx + 256] = acc1;
}

__global__ __launch_bounds__(256) void init_kernel(
    float* __restrict__ h, float* __restrict__ c, float* __restrict__ cur)
{
    int i = blockIdx.x * 256 + threadIdx.x;
    if (i < PB * PH) { h[i] = 0.0f; c[i] = 0.0f; }
    if (i < PB * PD) cur[i] = -1.0f;
}

// ---- fallback (Round-3 verified path) ----
template<class CA, class CO, int BM, int BN, int BK, int TM, int TN>
__global__ __launch_bounds__(256) void gemm_nt(
    const typename CA::T* __restrict__ A, const float* __restrict__ Bm,
    const float* __restrict__ bias, typename CO::T* __restrict__ C,
    int M, int N, int K)
{
    __shared__ float As[BK][BM];
    __shared__ float Bs[BK][BN];
    constexpr int TCOLS = BN / TN;
    constexpr int TROWS = BM / TM;
    static_assert(TCOLS * TROWS == 256, "thread tiling");
    const int tid = threadIdx.x;
    const int tc = tid % TCOLS;
    const int tr = tid / TCOLS;
    const int bm = blockIdx.y * BM;
    const int bn = blockIdx.x * BN;
    constexpr int AF4 = BM * BK / 4;
    constexpr int BF4 = BN * BK / 4;
    constexpr int KQ  = BK / 4;
    float acc[TM][TN];
    #pragma unroll
    for (int m = 0; m < TM; ++m)
        #pragma unroll
        for (int n = 0; n < TN; ++n) acc[m][n] = 0.0f;
    for (int k0 = 0; k0 < K; k0 += BK) {
        #pragma unroll
        for (int i = tid; i < AF4; i += 256) {
            int r = i / KQ, kq = i % KQ;
            float v4[4];
            CA::dec4(A + (size_t)(bm + r) * K + k0 + kq * 4, v4);
            As[kq*4+0][r] = v4[0]; As[kq*4+1][r] = v4[1];
            As[kq*4+2][r] = v4[2]; As[kq*4+3][r] = v4[3];
        }
        #pragma unroll
        for (int i = tid; i < BF4; i += 256) {
            int r = i / KQ, kq = i % KQ;
            const float4 v = *(const float4*)(Bm + (size_t)(bn + r) * K + k0 + kq * 4);
            Bs[kq*4+0][r] = v.x; Bs[kq*4+1][r] = v.y;
            Bs[kq*4+2][r] = v.z; Bs[kq*4+3][r] = v.w;
        }
        __syncthreads();
        #pragma unroll
        for (int k = 0; k < BK; ++k) {
            float av[TM], bv[TN];
            #pragma unroll
            for (int m = 0; m < TM; ++m) av[m] = As[k][tr * TM + m];
            #pragma unroll
            for (int n = 0; n < TN; ++n) bv[n] = Bs[k][tc * TN + n];
            #pragma unroll
            for (int m = 0; m < TM; ++m)
                #pragma unroll
                for (int n = 0; n < TN; ++n)
                    acc[m][n] = fmaf(av[m], bv[n], acc[m][n]);
        }
        __syncthreads();
    }
    #pragma unroll
    for (int m = 0; m < TM; ++m) {
        int row = bm + tr * TM + m;
        #pragma unroll
        for (int n = 0; n < TN; ++n) {
            int col = bn + tc * TN + n;
            float v = acc[m][n];
            if (bias) v += bias[col];
            C[(size_t)row * N + col] = CO::enc(v);
        }
    }
}

template<class CE>
__global__ __launch_bounds__(256) void lstm_cell(
    const float* __restrict__ z,
    const float* __restrict__ x, int x_stride,
    const float* __restrict__ Wih,
    const float* __restrict__ bih, const float* __restrict__ bhh,
    float* __restrict__ c, float* __restrict__ h,
    typename CE::T* __restrict__ extra, int extra_stride)
{
    int idx = blockIdx.x * 256 + threadIdx.x;
    int b = idx >> 9, j = idx & (PH - 1);
    float x0 = x[b * x_stride];
    float x1 = x[b * x_stride + 1];
    const float* zr = z + (size_t)b * P4H;
    float zi = zr[j]        + bih[j]        + bhh[j]        + x0 * Wih[2*j]          + x1 * Wih[2*j+1];
    float zf = zr[j + PH]   + bih[j + PH]   + bhh[j + PH]   + x0 * Wih[2*(j+PH)]     + x1 * Wih[2*(j+PH)+1];
    float zg = zr[j + 2*PH] + bih[j + 2*PH] + bhh[j + 2*PH] + x0 * Wih[2*(j+2*PH)]   + x1 * Wih[2*(j+2*PH)+1];
    float zo = zr[j + 3*PH] + bih[j + 3*PH] + bhh[j + 3*PH] + x0 * Wih[2*(j+3*PH)]   + x1 * Wih[2*(j+3*PH)+1];
    float cv = fast_sigmoid(zf) * c[idx] + fast_sigmoid(zi) * fast_tanh(zg);
    float hv = fast_sigmoid(zo) * fast_tanh(cv);
    c[idx] = cv;
    h[idx] = hv;
    if (extra) extra[(size_t)b * extra_stride + j] = CE::enc(hv);
}

// ===========================================================================
// Drivers
// ===========================================================================
struct Inputs {
    const float *inp, *enc_Wih, *enc_Whh, *enc_bih, *enc_bhh;
    const float *dec_Wih, *dec_Whh, *dec_bih, *dec_bhh;
    const float *W1, *b1, *W2, *b2, *v_w, *v_b, *comb_W, *comb_b;
};
static Inputs unpack(void* const* d_in) {
    Inputs in;
    in.inp = (const float*)d_in[0];
    in.enc_Wih = (const float*)d_in[1]; in.enc_Whh = (const float*)d_in[2];
    in.enc_bih = (const float*)d_in[3]; in.enc_bhh = (const float*)d_in[4];
    in.dec_Wih = (const float*)d_in[5]; in.dec_Whh = (const float*)d_in[6];
    in.dec_bih = (const float*)d_in[7]; in.dec_bhh = (const float*)d_in[8];
    in.W1 = (const float*)d_in[9];  in.b1 = (const float*)d_in[10];
    in.W2 = (const float*)d_in[11]; in.b2 = (const float*)d_in[12];
    in.v_w = (const float*)d_in[13]; in.v_b = (const float*)d_in[14];
    in.comb_W = (const float*)d_in[15]; in.comb_b = (const float*)d_in[16];
    return in;
}

static const size_t BIG = (size_t)PS * PB * PH;   // 33,554,432 elems

static void run_mfma(const Inputs& in, float* out, void* d_ws, hipStream_t stream)
{
    char* p = (char*)d_ws;
    auto alloc = [&](size_t bytes) { char* q_ = p; p += bytes; return q_; };
    u16* enc_out = (u16*)alloc(BIG * 2);
    u16* W1e     = (u16*)alloc(BIG * 2);
    u16* whh_e_hi = (u16*)alloc((size_t)P4H * PH * 2);
    u16* whh_e_lo = (u16*)alloc((size_t)P4H * PH * 2);
    u16* whh_d_hi = (u16*)alloc((size_t)P4H * PH * 2);
    u16* whh_d_lo = (u16*)alloc((size_t)P4H * PH * 2);
    u16* w1h = (u16*)alloc((size_t)PH * PH * 2);
    u16* w1l = (u16*)alloc((size_t)PH * PH * 2);
    u16* w2h = (u16*)alloc((size_t)PH * PH * 2);
    u16* w2l = (u16*)alloc((size_t)PH * PH * 2);
    u16* cwh = (u16*)alloc((size_t)PH * 2 * PH * 2);
    u16* cwl = (u16*)alloc((size_t)PH * 2 * PH * 2);
    float* wih_e = (float*)alloc((size_t)P4H * 2 * 4);
    float* wih_d = (float*)alloc((size_t)P4H * 2 * 4);
    float* bsum_e = (float*)alloc((size_t)P4H * 4);
    float* bsum_d = (float*)alloc((size_t)P4H * 4);
    float* hpp0 = (float*)alloc((size_t)PB * PH * 4);
    float* hpp1 = (float*)alloc((size_t)PB * PH * 4);
    float* cT   = (float*)alloc((size_t)PB * PH * 4);
    float* h0   = (float*)alloc((size_t)PB * PH * 4);
    float* q    = (float*)alloc((size_t)PB * PH * 4);
    float* catbuf = (float*)alloc((size_t)PB * 2 * PH * 4);
    float* u_t  = (float*)alloc((size_t)PB * PS * 4);
    float* a_buf = (float*)alloc((size_t)PB * PS * 4);
    float* cur  = (float*)alloc((size_t)PB * PD * 4);
    float* hpp[2] = { hpp0, hpp1 };

    // prep
    prep_whh<<<P4H, 256, 0, stream>>>(in.enc_Whh, whh_e_hi, whh_e_lo);
    prep_whh<<<P4H, 256, 0, stream>>>(in.dec_Whh, whh_d_hi, whh_d_lo);
    prep_split<<<PH, 256, 0, stream>>>(in.W1, w1h, w1l, PH);
    prep_split<<<PH, 256, 0, stream>>>(in.W2, w2h, w2l, PH);
    prep_split<<<PH, 256, 0, stream>>>(in.comb_W, cwh, cwl, 2 * PH);
    prep_small<<<P4H / 256, 256, 0, stream>>>(in.enc_Wih, in.enc_bih, in.enc_bhh, wih_e, bsum_e);
    prep_small<<<P4H / 256, 256, 0, stream>>>(in.dec_Wih, in.dec_bih, in.dec_bhh, wih_d, bsum_d);
    init_kernel<<<1024, 256, 0, stream>>>(hpp0, cT, cur);

    // encoder
    for (int s = 0; s < PS; ++s) {
        lstm_fused<1><<<dim3(PB / 64, P4H / 64), 256, 0, stream>>>(
            whh_e_hi, whh_e_lo, wih_e, bsum_e,
            in.inp + s * PD, PS * PD,
            hpp[s & 1], cT, hpp[(s + 1) & 1],
            enc_out + (size_t)s * PB * PH);
    }

    // W1e = enc_out @ W1.T + b1  (act bf16, out bf16)
    gemm_wtA<0, 1><<<dim3((PS * PB) / 64, PH / 64), 256, 0, stream>>>(
        w1h, w1l, enc_out, in.b1, W1e, PH, PH);

    // decoder
    for (int t = 0; t < PS; ++t) {
        lstm_fused<2><<<dim3(PB / 64, P4H / 64), 256, 0, stream>>>(
            whh_d_hi, whh_d_lo, wih_d, bsum_d,
            cur, PD,
            hpp[t & 1], cT, h0, catbuf);
        gemm_wtA<1, 0><<<dim3(PB / 64, PH / 64), 256, 0, stream>>>(
            w2h, w2l, h0, in.b2, q, PH, PH);
        u_pass<CBF16><<<(PS * PB) / 4, 256, 0, stream>>>(W1e, q, in.v_w, in.v_b, u_t);
        softmax_step<<<PB / 4, 256, 0, stream>>>(u_t, in.inp, a_buf, out, cur, t);
        ctx_kernel<CBF16><<<PB, 256, 0, stream>>>(enc_out, a_buf, catbuf);
        gemm_wtA<1, 0><<<dim3(PB / 64, PH / 64), 256, 0, stream>>>(
            cwh, cwl, catbuf, in.comb_b, hpp[(t + 1) & 1], 2 * PH, PH);
    }
}

static void run_fallback(const Inputs& in, float* out, void* d_ws, hipStream_t stream)
{
    char* p = (char*)d_ws;
    u16* enc_out = (u16*)p;  p += BIG * 2;
    u16* W1e     = (u16*)p;  p += BIG * 2;
    float* ws = (float*)p;
    size_t off = 0;
    auto alloc = [&](size_t n) { float* q_ = ws + off; off += n; return q_; };
    float* z      = alloc((size_t)PB * P4H);
    float* h      = alloc((size_t)PB * PH);
    float* c      = alloc((size_t)PB * PH);
    float* h0     = alloc((size_t)PB * PH);
    float* q      = alloc((size_t)PB * PH);
    float* catbuf = alloc((size_t)PB * 2 * PH);
    float* u_t    = alloc((size_t)PB * PS);
    float* a_buf  = alloc((size_t)PB * PS);
    float* cur    = alloc((size_t)PB * PD);

    init_kernel<<<1024, 256, 0, stream>>>(h, c, cur);
    for (int s = 0; s < PS; ++s) {
        gemm_nt<CF32, CF32, 64, 64, 32, 4, 4><<<dim3(P4H / 64, PB / 64), 256, 0, stream>>>(
            h, in.enc_Whh, nullptr, z, PB, P4H, PH);
        lstm_cell<CBF16><<<1024, 256, 0, stream>>>(
            z, in.inp + s * PD, PS * PD, in.enc_Wih, in.enc_bih, in.enc_bhh,
            c, h, enc_out + (size_t)s * PB * PH, PH);
    }
    gemm_nt<CBF16, CBF16, 64, 64, 32, 4, 4><<<dim3(PH / 64, (PS * PB) / 64), 256, 0, stream>>>(
        enc_out, in.W1, in.b1, W1e, PS * PB, PH, PH);
    for (int t = 0; t < PS; ++t) {
        gemm_nt<CF32, CF32, 64, 64, 32, 4, 4><<<dim3(P4H / 64, PB / 64), 256, 0, stream>>>(
            h, in.dec_Whh, nullptr, z, PB, P4H, PH);
        lstm_cell<CF32><<<1024, 256, 0, stream>>>(
            z, cur, PD, in.dec_Wih, in.dec_bih, in.dec_bhh,
            c, h0, catbuf + PH, 2 * PH);
        gemm_nt<CF32, CF32, 32, 32, 32, 2, 2><<<dim3(PH / 32, PB / 32), 256, 0, stream>>>(
            h0, in.W2, in.b2, q, PB, PH, PH);
        u_pass<CBF16><<<(PS * PB) / 4, 256, 0, stream>>>(W1e, q, in.v_w, in.v_b, u_t);
        softmax_step<<<PB / 4, 256, 0, stream>>>(u_t, in.inp, a_buf, out, cur, t);
        ctx_kernel<CBF16><<<PB, 256, 0, stream>>>(enc_out, a_buf, catbuf);
        gemm_nt<CF32, CF32, 32, 32, 32, 2, 2><<<dim3(PH / 32, PB / 32), 256, 0, stream>>>(
            catbuf, in.comb_W, in.comb_b, h, PB, PH, 2 * PH);
    }
}

extern "C" void kernel_launch(void* const* d_in, const int* in_sizes, int n_in,
                              void* d_out, int out_size, void* d_ws, size_t ws_size,
                              hipStream_t stream)
{
    Inputs in = unpack(d_in);
    float* out = (float*)d_out;

    const size_t mfma_need =
        BIG * 2 * 2 +                              // enc_out + W1e (bf16)
        (size_t)P4H * PH * 2 * 4 +                 // whh splits (enc+dec, hi+lo)
        (size_t)PH * PH * 2 * 4 +                  // w1, w2 splits
        (size_t)PH * 2 * PH * 2 * 2 +              // comb splits
        (size_t)P4H * 2 * 4 * 2 +                  // wih perms
        (size_t)P4H * 4 * 2 +                      // bsums
        ((size_t)PB * PH * 6 + (size_t)PB * PS * 2 + PB * PD) * 4; // f32 smalls
    const size_t fb_need =
        BIG * 2 * 2 +
        ((size_t)PB * P4H + 4 * (size_t)PB * PH + (size_t)PB * 2 * PH +
         2 * (size_t)PB * PS + (size_t)PB * PD) * 4;

    if (ws_size >= mfma_need)      run_mfma(in, out, d_ws, stream);
    else if (ws_size >= fb_need)   run_fallback(in, out, d_ws, stream);
    // else: insufficient workspace — nothing safe to do.
}

// Round 6
// 11781.532 us; speedup vs baseline: 2.0554x; 1.1428x over previous
//
#include <hip/hip_runtime.h>

// Problem constants: B=512, S=128, D=2, H=512, 4H=2048
#define PB 512
#define PS 128
#define PD 2
#define PH 512
#define P4H 2048

typedef unsigned int u32;
typedef unsigned short u16;
typedef __attribute__((ext_vector_type(8))) short short8;
typedef __attribute__((ext_vector_type(4))) float f32x4;

__device__ __forceinline__ float fast_sigmoid(float x) {
    return __fdividef(1.0f, 1.0f + __expf(-x));
}
__device__ __forceinline__ float fast_tanh(float x) {
    float ax = fabsf(x);
    float e = __expf(-2.0f * ax);
    float r = __fdividef(1.0f - e, 1.0f + e);
    return x < 0.0f ? -r : r;
}

__device__ __forceinline__ float bf_dec_u(u16 v) { return __uint_as_float((u32)v << 16); }
__device__ __forceinline__ u16 bf_trunc(float v) { return (u16)(__float_as_uint(v) >> 16); }
__device__ __forceinline__ u16 bf_rne(float v) {
    u32 u = __float_as_uint(v);
    return (u16)((u + 0x7FFFu + ((u >> 16) & 1u)) >> 16);
}
// split: v ~= hi + lo, residual ~2^-17 relative
__device__ __forceinline__ void bf_split(float v, u16& hi, u16& lo) {
    hi = bf_trunc(v);
    lo = bf_rne(v - bf_dec_u(hi));
}

struct CF32 {
    using T = float;
    static __device__ __forceinline__ float dec(T v) { return v; }
    static __device__ __forceinline__ T enc(float v) { return v; }
    static __device__ __forceinline__ void dec4(const T* p, float* o) {
        float4 v = *(const float4*)p; o[0]=v.x; o[1]=v.y; o[2]=v.z; o[3]=v.w;
    }
};
struct CBF16 {
    using T = u16;
    static __device__ __forceinline__ float dec(T v) { return __uint_as_float((u32)v << 16); }
    static __device__ __forceinline__ T enc(float v) { return bf_rne(v); }
    static __device__ __forceinline__ void dec4(const T* p, float* o) {
        uint2 v = *(const uint2*)p;
        o[0] = __uint_as_float(v.x << 16);
        o[1] = __uint_as_float(v.x & 0xFFFF0000u);
        o[2] = __uint_as_float(v.y << 16);
        o[3] = __uint_as_float(v.y & 0xFFFF0000u);
    }
};

// ===========================================================================
// Prep kernels
// ===========================================================================
// Permute Whh rows to gate-interleaved n' = 4j+g (orig n = g*512+j), split hi/lo.
// Optionally also emit permuted fp32 copy.
__global__ __launch_bounds__(256) void prep_whh(
    const float* __restrict__ Whh, u16* __restrict__ hi, u16* __restrict__ lo,
    float* __restrict__ f32out)
{
    int np = blockIdx.x;                 // 0..2047
    int j = np >> 2, g = np & 3;
    const float* src = Whh + (size_t)(g * PH + j) * PH;
    for (int k = threadIdx.x; k < PH; k += 256) {
        float v = src[k];
        u16 h_, l_;
        bf_split(v, h_, l_);
        hi[(size_t)np * PH + k] = h_;
        lo[(size_t)np * PH + k] = l_;
        if (f32out) f32out[(size_t)np * PH + k] = v;
    }
}
// Row-major [N][K] fp32 -> hi/lo bf16 split.
__global__ __launch_bounds__(256) void prep_split(
    const float* __restrict__ W, u16* __restrict__ hi, u16* __restrict__ lo, int K)
{
    int n = blockIdx.x;
    const float* src = W + (size_t)n * K;
    for (int k = threadIdx.x; k < K; k += 256) {
        u16 h_, l_;
        bf_split(src[k], h_, l_);
        hi[(size_t)n * K + k] = h_;
        lo[(size_t)n * K + k] = l_;
    }
}
// combT[m][k] = comb_W[k][m] (comb_W: [512][1024]) split to bf16 hi/lo.
__global__ __launch_bounds__(256) void prep_transpose_split(
    const float* __restrict__ W, u16* __restrict__ hi, u16* __restrict__ lo)
{
    __shared__ float tile[32][33];
    int m0 = blockIdx.x * 32;            // col base (0..1023)
    int k0 = blockIdx.y * 32;            // row base (0..511)
    int tx = threadIdx.x & 31, ty = threadIdx.x >> 5;   // ty 0..7
    #pragma unroll
    for (int i = 0; i < 4; ++i) {
        int k = k0 + ty + i * 8;
        tile[ty + i * 8][tx] = W[(size_t)k * (2 * PH) + m0 + tx];
    }
    __syncthreads();
    #pragma unroll
    for (int i = 0; i < 4; ++i) {
        int m = m0 + ty + i * 8;
        float v = tile[tx][ty + i * 8];
        u16 h_, l_; bf_split(v, h_, l_);
        hi[(size_t)m * PH + k0 + tx] = h_;
        lo[(size_t)m * PH + k0 + tx] = l_;
    }
}
// Permuted Wih [n'][2] fp32 and bsum[n'] = bih+bhh.
__global__ __launch_bounds__(256) void prep_small(
    const float* __restrict__ Wih, const float* __restrict__ bih,
    const float* __restrict__ bhh, float* __restrict__ wihp, float* __restrict__ bs)
{
    int np = blockIdx.x * 256 + threadIdx.x;
    if (np >= P4H) return;
    int j = np >> 2, g = np & 3;
    int n = g * PH + j;
    wihp[np * 2]     = Wih[(size_t)n * PD];
    wihp[np * 2 + 1] = Wih[(size_t)n * PD + 1];
    bs[np] = bih[n] + bhh[n];
}
// b_fused[n'] = dot(Whh_p_f32[n'], comb_b) + bsum_d[n']
__global__ __launch_bounds__(256) void prep_bfused(
    const float* __restrict__ whh_f32p, const float* __restrict__ comb_b,
    const float* __restrict__ bsum_d, float* __restrict__ bf)
{
    int np = blockIdx.x * 4 + (threadIdx.x >> 6);
    int lane = threadIdx.x & 63;
    const float* wr = whh_f32p + (size_t)np * PH + lane * 8;
    const float* cb = comb_b + lane * 8;
    float s = 0.0f;
    #pragma unroll
    for (int i = 0; i < 8; ++i) s += wr[i] * cb[i];
    #pragma unroll
    for (int off = 32; off; off >>= 1) s += __shfl_xor(s, off);
    if (lane == 0) bf[np] = s + bsum_d[np];
}

// ===========================================================================
// Fused LSTM step: z^T = W @ h^T via split-bf16 MFMA, cell in epilogue.
// KK = inner dim (512 raw-h, 1024 fused-cat). EXTRA_MODE: 0 none,
// 1 = bf16 h copy at extra[b*ex_stride + col], 2 = fp32 h copy same indexing.
// ===========================================================================
template<int EXTRA_MODE, int KK>
__global__ __launch_bounds__(256) void lstm_fused(
    const u16* __restrict__ Whh_hi, const u16* __restrict__ Whh_lo,
    const float* __restrict__ wih_perm, const float* __restrict__ bsum,
    const float* __restrict__ x, int x_stride,
    const float* __restrict__ h_in,    // [b][KK]
    float* __restrict__ cT,            // [j][b]
    float* __restrict__ h_out,         // [b][512]
    void* __restrict__ extra, int ex_stride)
{
    __shared__ u16 As_hi[64][72];
    __shared__ u16 As_lo[64][72];
    __shared__ u16 Bs_hi[64][72];
    __shared__ u16 Bs_lo[64][72];

    const int tid = threadIdx.x;
    const int bb = blockIdx.x * 64;     // b base
    const int bn = blockIdx.y * 64;     // n' base
    const int w = tid >> 6;
    const int wm = w >> 1, wn = w & 1;
    const int lane = tid & 63;
    const int l15 = lane & 15, lq = lane >> 4;

    f32x4 acc[2][2];
    #pragma unroll
    for (int i = 0; i < 2; ++i)
        #pragma unroll
        for (int j = 0; j < 2; ++j)
            acc[i][j] = (f32x4)0.0f;

    for (int k0 = 0; k0 < KK; k0 += 64) {
        #pragma unroll
        for (int rep = 0; rep < 2; ++rep) {
            int chunk = tid + rep * 256;
            int row = chunk >> 3, kc = (chunk & 7) * 8;
            *(uint4*)&As_hi[row][kc] = *(const uint4*)&Whh_hi[(size_t)(bn + row) * KK + k0 + kc];
            *(uint4*)&As_lo[row][kc] = *(const uint4*)&Whh_lo[(size_t)(bn + row) * KK + k0 + kc];
        }
        #pragma unroll
        for (int rep = 0; rep < 4; ++rep) {
            int chunk = tid + rep * 256;
            int row = chunk >> 4, kc = (chunk & 15) * 4;
            float4 v = *(const float4*)&h_in[(size_t)(bb + row) * KK + k0 + kc];
            u16 h0_, l0_, h1_, l1_, h2_, l2_, h3_, l3_;
            bf_split(v.x, h0_, l0_); bf_split(v.y, h1_, l1_);
            bf_split(v.z, h2_, l2_); bf_split(v.w, h3_, l3_);
            *(uint2*)&Bs_hi[row][kc] = make_uint2((u32)h0_ | ((u32)h1_ << 16),
                                                  (u32)h2_ | ((u32)h3_ << 16));
            *(uint2*)&Bs_lo[row][kc] = make_uint2((u32)l0_ | ((u32)l1_ << 16),
                                                  (u32)l2_ | ((u32)l3_ << 16));
        }
        __syncthreads();
        #pragma unroll
        for (int ks = 0; ks < 2; ++ks) {
            int kk = ks * 32 + lq * 8;
            short8 ah[2], al[2], bh[2], bl[2];
            #pragma unroll
            for (int mf = 0; mf < 2; ++mf) {
                int r = wm * 32 + mf * 16 + l15;
                ah[mf] = *(const short8*)&As_hi[r][kk];
                al[mf] = *(const short8*)&As_lo[r][kk];
            }
            #pragma unroll
            for (int nf = 0; nf < 2; ++nf) {
                int r = wn * 32 + nf * 16 + l15;
                bh[nf] = *(const short8*)&Bs_hi[r][kk];
                bl[nf] = *(const short8*)&Bs_lo[r][kk];
            }
            #pragma unroll
            for (int mf = 0; mf < 2; ++mf)
                #pragma unroll
                for (int nf = 0; nf < 2; ++nf) {
                    acc[mf][nf] = __builtin_amdgcn_mfma_f32_16x16x32_bf16(ah[mf], bh[nf], acc[mf][nf], 0, 0, 0);
                    acc[mf][nf] = __builtin_amdgcn_mfma_f32_16x16x32_bf16(ah[mf], bl[nf], acc[mf][nf], 0, 0, 0);
                    acc[mf][nf] = __builtin_amdgcn_mfma_f32_16x16x32_bf16(al[mf], bh[nf], acc[mf][nf], 0, 0, 0);
                }
        }
        __syncthreads();
    }

    // Epilogue: lane-local LSTM cell; h transposed via LDS for coalesced store.
    float* Hs = (float*)&As_hi[0][0];   // 16 x 66 floats = 4224 B < 9216 B
    #pragma unroll
    for (int nf = 0; nf < 2; ++nf) {
        int b_loc = wn * 32 + nf * 16 + l15;
        int b = bb + b_loc;
        float x0 = x[b * x_stride];
        float x1 = x[b * x_stride + 1];
        #pragma unroll
        for (int mf = 0; mf < 2; ++mf) {
            int np_loc = wm * 32 + mf * 16 + lq * 4;
            int np = bn + np_loc;
            float4 b4 = *(const float4*)&bsum[np];
            float4 wA = *(const float4*)&wih_perm[np * 2];
            float4 wB = *(const float4*)&wih_perm[np * 2 + 4];
            float zi = acc[mf][nf][0] + b4.x + x0 * wA.x + x1 * wA.y;
            float zf = acc[mf][nf][1] + b4.y + x0 * wA.z + x1 * wA.w;
            float zg = acc[mf][nf][2] + b4.z + x0 * wB.x + x1 * wB.y;
            float zo = acc[mf][nf][3] + b4.w + x0 * wB.z + x1 * wB.w;
            int jg = np >> 2;
            float cold = cT[(size_t)jg * PB + b];
            float cv = fast_sigmoid(zf) * cold + fast_sigmoid(zi) * fast_tanh(zg);
            float hv = fast_sigmoid(zo) * fast_tanh(cv);
            cT[(size_t)jg * PB + b] = cv;
            Hs[(np_loc >> 2) * 66 + b_loc] = hv;
        }
    }
    __syncthreads();
    {
        int b_loc = tid >> 2, jp = (tid & 3) * 4;
        int b = bb + b_loc;
        int jbase = bn >> 2;
        float4 hv4;
        hv4.x = Hs[(jp + 0) * 66 + b_loc];
        hv4.y = Hs[(jp + 1) * 66 + b_loc];
        hv4.z = Hs[(jp + 2) * 66 + b_loc];
        hv4.w = Hs[(jp + 3) * 66 + b_loc];
        *(float4*)&h_out[(size_t)b * PH + jbase + jp] = hv4;
        if (EXTRA_MODE == 1) {
            u16* e = (u16*)extra;
            *(uint2*)&e[(size_t)b * ex_stride + jbase + jp] =
                make_uint2((u32)bf_rne(hv4.x) | ((u32)bf_rne(hv4.y) << 16),
                           (u32)bf_rne(hv4.z) | ((u32)bf_rne(hv4.w) << 16));
        } else if (EXTRA_MODE == 2) {
            float* e = (float*)extra;
            *(float4*)&e[(size_t)b * ex_stride + jbase + jp] = hv4;
        }
    }
}

// ===========================================================================
// MFMA GEMM, weights-as-A: out[m][n] = act[m,:] . W[n,:] + bias[n]
// OUTMODE: 0 fp32, 1 bf16, 2 split hi/lo (out, out2)
// ===========================================================================
template<int ACT_F32, int OUTMODE>
__global__ __launch_bounds__(256) void gemm_wtA(
    const u16* __restrict__ Whi, const u16* __restrict__ Wlo,
    const void* __restrict__ act, const float* __restrict__ bias,
    void* __restrict__ out, void* __restrict__ out2, int K, int ldo)
{
    __shared__ u16 As_hi[64][72];
    __shared__ u16 As_lo[64][72];
    __shared__ u16 Bs_hi[64][72];
    __shared__ u16 Bs_lo[64][72];

    const int tid = threadIdx.x;
    const int bm = blockIdx.x * 64;     // act-row base
    const int bn = blockIdx.y * 64;     // weight-row base
    const int w = tid >> 6;
    const int wm = w >> 1, wn = w & 1;
    const int lane = tid & 63;
    const int l15 = lane & 15, lq = lane >> 4;

    f32x4 acc[2][2];
    #pragma unroll
    for (int i = 0; i < 2; ++i)
        #pragma unroll
        for (int j = 0; j < 2; ++j)
            acc[i][j] = (f32x4)0.0f;

    for (int k0 = 0; k0 < K; k0 += 64) {
        #pragma unroll
        for (int rep = 0; rep < 2; ++rep) {
            int chunk = tid + rep * 256;
            int row = chunk >> 3, kc = (chunk & 7) * 8;
            *(uint4*)&As_hi[row][kc] = *(const uint4*)&Whi[(size_t)(bn + row) * K + k0 + kc];
            *(uint4*)&As_lo[row][kc] = *(const uint4*)&Wlo[(size_t)(bn + row) * K + k0 + kc];
        }
        if (ACT_F32) {
            const float* a = (const float*)act;
            #pragma unroll
            for (int rep = 0; rep < 4; ++rep) {
                int chunk = tid + rep * 256;
                int row = chunk >> 4, kc = (chunk & 15) * 4;
                float4 v = *(const float4*)&a[(size_t)(bm + row) * K + k0 + kc];
                u16 h0_, l0_, h1_, l1_, h2_, l2_, h3_, l3_;
                bf_split(v.x, h0_, l0_); bf_split(v.y, h1_, l1_);
                bf_split(v.z, h2_, l2_); bf_split(v.w, h3_, l3_);
                *(uint2*)&Bs_hi[row][kc] = make_uint2((u32)h0_ | ((u32)h1_ << 16),
                                                      (u32)h2_ | ((u32)h3_ << 16));
                *(uint2*)&Bs_lo[row][kc] = make_uint2((u32)l0_ | ((u32)l1_ << 16),
                                                      (u32)l2_ | ((u32)l3_ << 16));
            }
        } else {
            const u16* a = (const u16*)act;
            #pragma unroll
            for (int rep = 0; rep < 2; ++rep) {
                int chunk = tid + rep * 256;
                int row = chunk >> 3, kc = (chunk & 7) * 8;
                *(uint4*)&Bs_hi[row][kc] = *(const uint4*)&a[(size_t)(bm + row) * K + k0 + kc];
            }
        }
        __syncthreads();
        #pragma unroll
        for (int ks = 0; ks < 2; ++ks) {
            int kk = ks * 32 + lq * 8;
            short8 ah[2], al[2], bh[2], bl[2];
            #pragma unroll
            for (int mf = 0; mf < 2; ++mf) {
                int r = wm * 32 + mf * 16 + l15;
                ah[mf] = *(const short8*)&As_hi[r][kk];
                al[mf] = *(const short8*)&As_lo[r][kk];
            }
            #pragma unroll
            for (int nf = 0; nf < 2; ++nf) {
                int r = wn * 32 + nf * 16 + l15;
                bh[nf] = *(const short8*)&Bs_hi[r][kk];
                if (ACT_F32) bl[nf] = *(const short8*)&Bs_lo[r][kk];
            }
            #pragma unroll
            for (int mf = 0; mf < 2; ++mf)
                #pragma unroll
                for (int nf = 0; nf < 2; ++nf) {
                    acc[mf][nf] = __builtin_amdgcn_mfma_f32_16x16x32_bf16(ah[mf], bh[nf], acc[mf][nf], 0, 0, 0);
                    if (ACT_F32) {
                        acc[mf][nf] = __builtin_amdgcn_mfma_f32_16x16x32_bf16(ah[mf], bl[nf], acc[mf][nf], 0, 0, 0);
                        acc[mf][nf] = __builtin_amdgcn_mfma_f32_16x16x32_bf16(al[mf], bh[nf], acc[mf][nf], 0, 0, 0);
                    } else {
                        acc[mf][nf] = __builtin_amdgcn_mfma_f32_16x16x32_bf16(al[mf], bh[nf], acc[mf][nf], 0, 0, 0);
                    }
                }
        }
        __syncthreads();
    }

    #pragma unroll
    for (int nf = 0; nf < 2; ++nf) {
        int m = bm + wn * 32 + nf * 16 + l15;
        #pragma unroll
        for (int mf = 0; mf < 2; ++mf) {
            int n = bn + wm * 32 + mf * 16 + lq * 4;
            float4 b4 = bias ? *(const float4*)&bias[n] : make_float4(0.f, 0.f, 0.f, 0.f);
            float v0 = acc[mf][nf][0] + b4.x;
            float v1 = acc[mf][nf][1] + b4.y;
            float v2 = acc[mf][nf][2] + b4.z;
            float v3 = acc[mf][nf][3] + b4.w;
            if (OUTMODE == 1) {
                u16* o = (u16*)out;
                *(uint2*)&o[(size_t)m * ldo + n] =
                    make_uint2((u32)bf_rne(v0) | ((u32)bf_rne(v1) << 16),
                               (u32)bf_rne(v2) | ((u32)bf_rne(v3) << 16));
            } else if (OUTMODE == 2) {
                u16 h0_, l0_, h1_, l1_, h2_, l2_, h3_, l3_;
                bf_split(v0, h0_, l0_); bf_split(v1, h1_, l1_);
                bf_split(v2, h2_, l2_); bf_split(v3, h3_, l3_);
                u16* oh = (u16*)out;
                u16* ol = (u16*)out2;
                *(uint2*)&oh[(size_t)m * ldo + n] =
                    make_uint2((u32)h0_ | ((u32)h1_ << 16), (u32)h2_ | ((u32)h3_ << 16));
                *(uint2*)&ol[(size_t)m * ldo + n] =
                    make_uint2((u32)l0_ | ((u32)l1_ << 16), (u32)l2_ | ((u32)l3_ << 16));
            } else {
                float* o = (float*)out;
                *(float4*)&o[(size_t)m * ldo + n] = make_float4(v0, v1, v2, v3);
            }
        }
    }
}

// ===========================================================================
// Fused attention step: u = v.tanh(W1e[b,s,:]+q[b,:]) -> softmax/argmax ->
// out row, cur gather, ctx -> cat_out left half.  One block per b.
// ===========================================================================
__global__ __launch_bounds__(256) void attn_fused(
    const u16* __restrict__ W1e,      // [b][s][h] bf16
    const u16* __restrict__ enc_out,  // [b][s][h] bf16
    const float* __restrict__ qv,     // [b][512]
    const float* __restrict__ v_w, const float* __restrict__ v_b,
    const float* __restrict__ inp,
    float* __restrict__ out,
    float* __restrict__ cat_out,      // [b][1024] (left half written)
    float* __restrict__ cur, int t)
{
    __shared__ float u_s[PS];
    __shared__ float a_s[PS];
    const int b = blockIdx.x;
    const int tid = threadIdx.x;
    const int w = tid >> 6, lane = tid & 63;

    float q8[8], v8[8];
    {
        const float* qr = qv + (size_t)b * PH + lane * 8;
        CF32::dec4(qr, q8); CF32::dec4(qr + 4, q8 + 4);
        const float* vr = v_w + lane * 8;
        CF32::dec4(vr, v8); CF32::dec4(vr + 4, v8 + 4);
    }
    const float vb = v_b[0];
    const u16* wbase = W1e + (size_t)b * PS * PH + lane * 8;
    #pragma unroll 2
    for (int i = 0; i < 32; ++i) {
        int s = w * 32 + i;
        const u16* row = wbase + (size_t)s * PH;
        float w8[8];
        CBF16::dec4(row, w8); CBF16::dec4(row + 4, w8 + 4);
        float sum = 0.0f;
        #pragma unroll
        for (int j = 0; j < 8; ++j) sum += v8[j] * fast_tanh(w8[j] + q8[j]);
        #pragma unroll
        for (int off = 32; off; off >>= 1) sum += __shfl_xor(sum, off);
        if (lane == 0) u_s[s] = sum + vb;
    }
    __syncthreads();
    if (w == 0) {
        float2 uv = make_float2(u_s[lane * 2], u_s[lane * 2 + 1]);
        float m = fmaxf(uv.x, uv.y);
        int mi = (uv.y > uv.x) ? (lane * 2 + 1) : (lane * 2);
        #pragma unroll
        for (int off = 32; off; off >>= 1) {
            float om = __shfl_xor(m, off);
            int oi = __shfl_xor(mi, off);
            if (om > m || (om == m && oi < mi)) { m = om; mi = oi; }
        }
        float e0 = __expf(uv.x - m);
        float e1 = __expf(uv.y - m);
        float ssum = e0 + e1;
        #pragma unroll
        for (int off = 32; off; off >>= 1) ssum += __shfl_xor(ssum, off);
        float inv = __fdividef(1.0f, ssum);
        float2 av = make_float2(e0 * inv, e1 * inv);
        a_s[lane * 2] = av.x; a_s[lane * 2 + 1] = av.y;
        *(float2*)&out[(size_t)b * PS * PS + (size_t)t * PS + lane * 2] = av;
        if (lane == 0) {
            cur[b * 2]     = inp[(size_t)b * PS * PD + mi * PD];
            cur[b * 2 + 1] = inp[(size_t)b * PS * PD + mi * PD + 1];
        }
    }
    __syncthreads();
    float acc0 = 0.0f, acc1 = 0.0f;
    const u16* ebase = enc_out + (size_t)b * PS * PH + tid * 2;
    #pragma unroll 4
    for (int s = 0; s < PS; ++s) {
        float a = a_s[s];
        u32 pr = *(const u32*)(ebase + (size_t)s * PH);
        acc0 = fmaf(a, __uint_as_float(pr << 16), acc0);
        acc1 = fmaf(a, __uint_as_float(pr & 0xFFFF0000u), acc1);
    }
    *(float2*)&cat_out[(size_t)b * (2 * PH) + tid * 2] = make_float2(acc0, acc1);
}

// ===========================================================================
// Tier-2/3 kernels (Round-4 verified paths)
// ===========================================================================
template<class C>
__global__ __launch_bounds__(256) void u_pass(
    const typename C::T* __restrict__ W1e, const float* __restrict__ q,
    const float* __restrict__ v_w, const float* __restrict__ v_b,
    float* __restrict__ u_t)
{
    int row = blockIdx.x * 4 + (threadIdx.x >> 6);  // row = s*B + b
    int lane = threadIdx.x & 63;
    int s = row >> 9;
    int b = row & (PB - 1);
    const typename C::T* wr = W1e + (size_t)row * PH + lane * 8;
    const float* qr = q + (size_t)b * PH + lane * 8;
    const float* vr = v_w + lane * 8;
    float w8[8], q8[8], v8[8];
    C::dec4(wr, w8); C::dec4(wr + 4, w8 + 4);
    CF32::dec4(qr, q8); CF32::dec4(qr + 4, q8 + 4);
    CF32::dec4(vr, v8); CF32::dec4(vr + 4, v8 + 4);
    float sum = 0.0f;
    #pragma unroll
    for (int i = 0; i < 8; ++i)
        sum += v8[i] * fast_tanh(w8[i] + q8[i]);
    #pragma unroll
    for (int off = 32; off; off >>= 1) sum += __shfl_xor(sum, off);
    if (lane == 0) u_t[b * PS + s] = sum + v_b[0];
}

__global__ __launch_bounds__(256) void softmax_step(
    const float* __restrict__ u_t, const float* __restrict__ inp,
    float* __restrict__ a_buf, float* __restrict__ out,
    float* __restrict__ cur, int t)
{
    int b = blockIdx.x * 4 + (threadIdx.x >> 6);
    int lane = threadIdx.x & 63;
    float2 uv = *(const float2*)&u_t[b * PS + lane * 2];
    float m = fmaxf(uv.x, uv.y);
    int mi = (uv.y > uv.x) ? (lane * 2 + 1) : (lane * 2);
    #pragma unroll
    for (int off = 32; off; off >>= 1) {
        float om = __shfl_xor(m, off);
        int oi = __shfl_xor(mi, off);
        if (om > m || (om == m && oi < mi)) { m = om; mi = oi; }
    }
    float e0 = __expf(uv.x - m);
    float e1 = __expf(uv.y - m);
    float ssum = e0 + e1;
    #pragma unroll
    for (int off = 32; off; off >>= 1) ssum += __shfl_xor(ssum, off);
    float inv = __fdividef(1.0f, ssum);
    float2 av = make_float2(e0 * inv, e1 * inv);
    *(float2*)&a_buf[b * PS + lane * 2] = av;
    *(float2*)&out[(size_t)b * PS * PS + (size_t)t * PS + lane * 2] = av;
    if (lane == 0) {
        cur[b * 2]     = inp[(size_t)b * PS * PD + mi * PD];
        cur[b * 2 + 1] = inp[(size_t)b * PS * PD + mi * PD + 1];
    }
}

template<class C>
__global__ __launch_bounds__(256) void ctx_kernel(
    const typename C::T* __restrict__ enc_out, const float* __restrict__ a_buf,
    float* __restrict__ catbuf)
{
    int b = blockIdx.x;
    int hidx = threadIdx.x;
    const float* ab = a_buf + b * PS;
    const typename C::T* e = enc_out + (size_t)b * PH;
    float acc0 = 0.0f, acc1 = 0.0f;
    #pragma unroll 4
    for (int s = 0; s < PS; ++s) {
        float a = ab[s];
        const typename C::T* es = e + (size_t)s * PB * PH;
        acc0 = fmaf(a, C::dec(es[hidx]), acc0);
        acc1 = fmaf(a, C::dec(es[hidx + 256]), acc1);
    }
    catbuf[(size_t)b * (2 * PH) + hidx] = acc0;
    catbuf[(size_t)b * (2 * PH) + hidx + 256] = acc1;
}

__global__ __launch_bounds__(256) void init_kernel(
    float* __restrict__ h, float* __restrict__ c, float* __restrict__ cur)
{
    int i = blockIdx.x * 256 + threadIdx.x;
    if (i < PB * PH) { h[i] = 0.0f; c[i] = 0.0f; }
    if (i < PB * PD) cur[i] = -1.0f;
}

template<class CA, class CO, int BM, int BN, int BK, int TM, int TN>
__global__ __launch_bounds__(256) void gemm_nt(
    const typename CA::T* __restrict__ A, const float* __restrict__ Bm,
    const float* __restrict__ bias, typename CO::T* __restrict__ C,
    int M, int N, int K)
{
    __shared__ float As[BK][BM];
    __shared__ float Bs[BK][BN];
    constexpr int TCOLS = BN / TN;
    constexpr int TROWS = BM / TM;
    static_assert(TCOLS * TROWS == 256, "thread tiling");
    const int tid = threadIdx.x;
    const int tc = tid % TCOLS;
    const int tr = tid / TCOLS;
    const int bm = blockIdx.y * BM;
    const int bn = blockIdx.x * BN;
    constexpr int AF4 = BM * BK / 4;
    constexpr int BF4 = BN * BK / 4;
    constexpr int KQ  = BK / 4;
    float acc[TM][TN];
    #pragma unroll
    for (int m = 0; m < TM; ++m)
        #pragma unroll
        for (int n = 0; n < TN; ++n) acc[m][n] = 0.0f;
    for (int k0 = 0; k0 < K; k0 += BK) {
        #pragma unroll
        for (int i = tid; i < AF4; i += 256) {
            int r = i / KQ, kq = i % KQ;
            float v4[4];
            CA::dec4(A + (size_t)(bm + r) * K + k0 + kq * 4, v4);
            As[kq*4+0][r] = v4[0]; As[kq*4+1][r] = v4[1];
            As[kq*4+2][r] = v4[2]; As[kq*4+3][r] = v4[3];
        }
        #pragma unroll
        for (int i = tid; i < BF4; i += 256) {
            int r = i / KQ, kq = i % KQ;
            const float4 v = *(const float4*)(Bm + (size_t)(bn + r) * K + k0 + kq * 4);
            Bs[kq*4+0][r] = v.x; Bs[kq*4+1][r] = v.y;
            Bs[kq*4+2][r] = v.z; Bs[kq*4+3][r] = v.w;
        }
        __syncthreads();
        #pragma unroll
        for (int k = 0; k < BK; ++k) {
            float av[TM], bv[TN];
            #pragma unroll
            for (int m = 0; m < TM; ++m) av[m] = As[k][tr * TM + m];
            #pragma unroll
            for (int n = 0; n < TN; ++n) bv[n] = Bs[k][tc * TN + n];
            #pragma unroll
            for (int m = 0; m < TM; ++m)
                #pragma unroll
                for (int n = 0; n < TN; ++n)
                    acc[m][n] = fmaf(av[m], bv[n], acc[m][n]);
        }
        __syncthreads();
    }
    #pragma unroll
    for (int m = 0; m < TM; ++m) {
        int row = bm + tr * TM + m;
        #pragma unroll
        for (int n = 0; n < TN; ++n) {
            int col = bn + tc * TN + n;
            float v = acc[m][n];
            if (bias) v += bias[col];
            C[(size_t)row * N + col] = CO::enc(v);
        }
    }
}

template<class CE>
__global__ __launch_bounds__(256) void lstm_cell(
    const float* __restrict__ z,
    const float* __restrict__ x, int x_stride,
    const float* __restrict__ Wih,
    const float* __restrict__ bih, const float* __restrict__ bhh,
    float* __restrict__ c, float* __restrict__ h,
    typename CE::T* __restrict__ extra, int extra_stride)
{
    int idx = blockIdx.x * 256 + threadIdx.x;
    int b = idx >> 9, j = idx & (PH - 1);
    float x0 = x[b * x_stride];
    float x1 = x[b * x_stride + 1];
    const float* zr = z + (size_t)b * P4H;
    float zi = zr[j]        + bih[j]        + bhh[j]        + x0 * Wih[2*j]          + x1 * Wih[2*j+1];
    float zf = zr[j + PH]   + bih[j + PH]   + bhh[j + PH]   + x0 * Wih[2*(j+PH)]     + x1 * Wih[2*(j+PH)+1];
    float zg = zr[j + 2*PH] + bih[j + 2*PH] + bhh[j + 2*PH] + x0 * Wih[2*(j+2*PH)]   + x1 * Wih[2*(j+2*PH)+1];
    float zo = zr[j + 3*PH] + bih[j + 3*PH] + bhh[j + 3*PH] + x0 * Wih[2*(j+3*PH)]   + x1 * Wih[2*(j+3*PH)+1];
    float cv = fast_sigmoid(zf) * c[idx] + fast_sigmoid(zi) * fast_tanh(zg);
    float hv = fast_sigmoid(zo) * fast_tanh(cv);
    c[idx] = cv;
    h[idx] = hv;
    if (extra) extra[(size_t)b * extra_stride + j] = CE::enc(hv);
}

// ===========================================================================
// Drivers
// ===========================================================================
struct Inputs {
    const float *inp, *enc_Wih, *enc_Whh, *enc_bih, *enc_bhh;
    const float *dec_Wih, *dec_Whh, *dec_bih, *dec_bhh;
    const float *W1, *b1, *W2, *b2, *v_w, *v_b, *comb_W, *comb_b;
};
static Inputs unpack(void* const* d_in) {
    Inputs in;
    in.inp = (const float*)d_in[0];
    in.enc_Wih = (const float*)d_in[1]; in.enc_Whh = (const float*)d_in[2];
    in.enc_bih = (const float*)d_in[3]; in.enc_bhh = (const float*)d_in[4];
    in.dec_Wih = (const float*)d_in[5]; in.dec_Whh = (const float*)d_in[6];
    in.dec_bih = (const float*)d_in[7]; in.dec_bhh = (const float*)d_in[8];
    in.W1 = (const float*)d_in[9];  in.b1 = (const float*)d_in[10];
    in.W2 = (const float*)d_in[11]; in.b2 = (const float*)d_in[12];
    in.v_w = (const float*)d_in[13]; in.v_b = (const float*)d_in[14];
    in.comb_W = (const float*)d_in[15]; in.comb_b = (const float*)d_in[16];
    return in;
}

static const size_t BIG = (size_t)PS * PB * PH;   // 33,554,432 elems

// ---------------- Tier 1: fused-comb + fused-attn (this round) -------------
static void run_mfma2(const Inputs& in, float* out, void* d_ws, hipStream_t stream)
{
    char* p = (char*)d_ws;
    auto alloc = [&](size_t bytes) { char* r = p; p += bytes; return r; };
    u16* enc_out  = (u16*)alloc(BIG * 2);                     // [b][s][h]
    u16* W1e      = (u16*)alloc(BIG * 2);                     // [b][s][h]
    u16* whh_e_hi = (u16*)alloc((size_t)P4H * PH * 2);        // encoder-only
    u16* whh_e_lo = (u16*)alloc((size_t)P4H * PH * 2);        // encoder-only
    u16* whh_d_hi = (u16*)alloc((size_t)P4H * PH * 2);
    u16* whh_d_lo = (u16*)alloc((size_t)P4H * PH * 2);
    u16* w1h = (u16*)alloc((size_t)PH * PH * 2);
    u16* w1l = (u16*)alloc((size_t)PH * PH * 2);
    u16* w2h = (u16*)alloc((size_t)PH * PH * 2);
    u16* w2l = (u16*)alloc((size_t)PH * PH * 2);
    u16* ctw_h = (u16*)alloc((size_t)(2 * PH) * PH * 2);      // combT split
    u16* ctw_l = (u16*)alloc((size_t)(2 * PH) * PH * 2);
    u16* wf_h = (u16*)alloc((size_t)P4H * (2 * PH) * 2);      // W_fused split
    u16* wf_l = (u16*)alloc((size_t)P4H * (2 * PH) * 2);
    float* wih_e = (float*)alloc((size_t)P4H * 2 * 4);
    float* wih_d = (float*)alloc((size_t)P4H * 2 * 4);
    float* bsum_e = (float*)alloc((size_t)P4H * 4);
    float* bsum_d = (float*)alloc((size_t)P4H * 4);
    float* b_fus  = (float*)alloc((size_t)P4H * 4);
    float* hpp0 = (float*)alloc((size_t)PB * PH * 4);
    float* hpp1 = (float*)alloc((size_t)PB * PH * 4);
    float* cT   = (float*)alloc((size_t)PB * PH * 4);
    float* catreg = (float*)alloc((size_t)PB * 2 * PH * 4 * 2);  // 2 buffers
    float* cur  = (float*)alloc((size_t)PB * PD * 4);
    // aliases (stream-serial lifetime separation):
    float* whh_f32p = catreg;               // prep-only; cat written from t=0 on
    float* h0 = (float*)whh_e_hi;           // decoder-only; encoder done by then
    float* q  = (float*)whh_e_lo;
    float* cat[2] = { catreg, catreg + (size_t)PB * 2 * PH };
    float* hpp[2] = { hpp0, hpp1 };

    // ---- prep ----
    prep_whh<<<P4H, 256, 0, stream>>>(in.enc_Whh, whh_e_hi, whh_e_lo, nullptr);
    prep_whh<<<P4H, 256, 0, stream>>>(in.dec_Whh, whh_d_hi, whh_d_lo, whh_f32p);
    prep_split<<<PH, 256, 0, stream>>>(in.W1, w1h, w1l, PH);
    prep_split<<<PH, 256, 0, stream>>>(in.W2, w2h, w2l, PH);
    prep_transpose_split<<<dim3(32, 16), 256, 0, stream>>>(in.comb_W, ctw_h, ctw_l);
    prep_small<<<P4H / 256, 256, 0, stream>>>(in.enc_Wih, in.enc_bih, in.enc_bhh, wih_e, bsum_e);
    prep_small<<<P4H / 256, 256, 0, stream>>>(in.dec_Wih, in.dec_bih, in.dec_bhh, wih_d, bsum_d);
    // W_fused[n'][m] = Whh_p[n',:] . combT[m,:], split-epilogue
    gemm_wtA<1, 2><<<dim3(P4H / 64, (2 * PH) / 64), 256, 0, stream>>>(
        ctw_h, ctw_l, whh_f32p, nullptr, wf_h, wf_l, PH, 2 * PH);
    prep_bfused<<<P4H / 4, 256, 0, stream>>>(whh_f32p, in.comb_b, bsum_d, b_fus);
    init_kernel<<<1024, 256, 0, stream>>>(hpp0, cT, cur);

    // ---- encoder ----
    for (int s = 0; s < PS; ++s) {
        lstm_fused<1, PH><<<dim3(PB / 64, P4H / 64), 256, 0, stream>>>(
            whh_e_hi, whh_e_lo, wih_e, bsum_e,
            in.inp + s * PD, PS * PD,
            hpp[s & 1], cT, hpp[(s + 1) & 1],
            enc_out + (size_t)s * PH, PS * PH);
    }

    // ---- W1e = enc_out @ W1.T + b1 ----
    gemm_wtA<0, 1><<<dim3((PS * PB) / 64, PH / 64), 256, 0, stream>>>(
        w1h, w1l, enc_out, in.b1, W1e, nullptr, PH, PH);

    // ---- decoder: 3 kernels/step ----
    for (int t = 0; t < PS; ++t) {
        float* cat_out = cat[(t + 1) & 1];
        if (t == 0) {
            lstm_fused<2, PH><<<dim3(PB / 64, P4H / 64), 256, 0, stream>>>(
                whh_d_hi, whh_d_lo, wih_d, bsum_d,
                cur, PD, hpp[0], cT, h0, cat_out + PH, 2 * PH);
        } else {
            lstm_fused<2, 2 * PH><<<dim3(PB / 64, P4H / 64), 256, 0, stream>>>(
                wf_h, wf_l, wih_d, b_fus,
                cur, PD, cat[t & 1], cT, h0, cat_out + PH, 2 * PH);
        }
        gemm_wtA<1, 0><<<dim3(PB / 64, PH / 64), 256, 0, stream>>>(
            w2h, w2l, h0, in.b2, q, nullptr, PH, PH);
        attn_fused<<<PB, 256, 0, stream>>>(
            W1e, enc_out, q, in.v_w, in.v_b, in.inp, out, cat_out, cur, t);
    }
}

// ---------------- Tier 2: Round-4 verified MFMA path ----------------------
static void run_mfma(const Inputs& in, float* out, void* d_ws, hipStream_t stream)
{
    char* p = (char*)d_ws;
    auto alloc = [&](size_t bytes) { char* r = p; p += bytes; return r; };
    u16* enc_out = (u16*)alloc(BIG * 2);                      // [s][b][h]
    u16* W1e     = (u16*)alloc(BIG * 2);                      // [s*B+b][h]
    u16* whh_e_hi = (u16*)alloc((size_t)P4H * PH * 2);
    u16* whh_e_lo = (u16*)alloc((size_t)P4H * PH * 2);
    u16* whh_d_hi = (u16*)alloc((size_t)P4H * PH * 2);
    u16* whh_d_lo = (u16*)alloc((size_t)P4H * PH * 2);
    u16* w1h = (u16*)alloc((size_t)PH * PH * 2);
    u16* w1l = (u16*)alloc((size_t)PH * PH * 2);
    u16* w2h = (u16*)alloc((size_t)PH * PH * 2);
    u16* w2l = (u16*)alloc((size_t)PH * PH * 2);
    u16* cwh = (u16*)alloc((size_t)PH * 2 * PH * 2);
    u16* cwl = (u16*)alloc((size_t)PH * 2 * PH * 2);
    float* wih_e = (float*)alloc((size_t)P4H * 2 * 4);
    float* wih_d = (float*)alloc((size_t)P4H * 2 * 4);
    float* bsum_e = (float*)alloc((size_t)P4H * 4);
    float* bsum_d = (float*)alloc((size_t)P4H * 4);
    float* hpp0 = (float*)alloc((size_t)PB * PH * 4);
    float* hpp1 = (float*)alloc((size_t)PB * PH * 4);
    float* cT   = (float*)alloc((size_t)PB * PH * 4);
    float* h0   = (float*)alloc((size_t)PB * PH * 4);
    float* q    = (float*)alloc((size_t)PB * PH * 4);
    float* catbuf = (float*)alloc((size_t)PB * 2 * PH * 4);
    float* u_t  = (float*)alloc((size_t)PB * PS * 4);
    float* a_buf = (float*)alloc((size_t)PB * PS * 4);
    float* cur  = (float*)alloc((size_t)PB * PD * 4);
    float* hpp[2] = { hpp0, hpp1 };

    prep_whh<<<P4H, 256, 0, stream>>>(in.enc_Whh, whh_e_hi, whh_e_lo, nullptr);
    prep_whh<<<P4H, 256, 0, stream>>>(in.dec_Whh, whh_d_hi, whh_d_lo, nullptr);
    prep_split<<<PH, 256, 0, stream>>>(in.W1, w1h, w1l, PH);
    prep_split<<<PH, 256, 0, stream>>>(in.W2, w2h, w2l, PH);
    prep_split<<<PH, 256, 0, stream>>>(in.comb_W, cwh, cwl, 2 * PH);
    prep_small<<<P4H / 256, 256, 0, stream>>>(in.enc_Wih, in.enc_bih, in.enc_bhh, wih_e, bsum_e);
    prep_small<<<P4H / 256, 256, 0, stream>>>(in.dec_Wih, in.dec_bih, in.dec_bhh, wih_d, bsum_d);
    init_kernel<<<1024, 256, 0, stream>>>(hpp0, cT, cur);

    for (int s = 0; s < PS; ++s) {
        lstm_fused<1, PH><<<dim3(PB / 64, P4H / 64), 256, 0, stream>>>(
            whh_e_hi, whh_e_lo, wih_e, bsum_e,
            in.inp + s * PD, PS * PD,
            hpp[s & 1], cT, hpp[(s + 1) & 1],
            enc_out + (size_t)s * PB * PH, PH);
    }
    gemm_wtA<0, 1><<<dim3((PS * PB) / 64, PH / 64), 256, 0, stream>>>(
        w1h, w1l, enc_out, in.b1, W1e, nullptr, PH, PH);
    for (int t = 0; t < PS; ++t) {
        lstm_fused<2, PH><<<dim3(PB / 64, P4H / 64), 256, 0, stream>>>(
            whh_d_hi, whh_d_lo, wih_d, bsum_d,
            cur, PD, hpp[t & 1], cT, h0, catbuf + PH, 2 * PH);
        gemm_wtA<1, 0><<<dim3(PB / 64, PH / 64), 256, 0, stream>>>(
            w2h, w2l, h0, in.b2, q, nullptr, PH, PH);
        u_pass<CBF16><<<(PS * PB) / 4, 256, 0, stream>>>(W1e, q, in.v_w, in.v_b, u_t);
        softmax_step<<<PB / 4, 256, 0, stream>>>(u_t, in.inp, a_buf, out, cur, t);
        ctx_kernel<CBF16><<<PB, 256, 0, stream>>>(enc_out, a_buf, catbuf);
        gemm_wtA<1, 0><<<dim3(PB / 64, PH / 64), 256, 0, stream>>>(
            cwh, cwl, catbuf, in.comb_b, hpp[(t + 1) & 1], nullptr, 2 * PH, PH);
    }
}

// ---------------- Tier 3: vector-ALU fallback ------------------------------
static void run_fallback(const Inputs& in, float* out, void* d_ws, hipStream_t stream)
{
    char* p = (char*)d_ws;
    u16* enc_out = (u16*)p;  p += BIG * 2;
    u16* W1e     = (u16*)p;  p += BIG * 2;
    float* ws = (float*)p;
    size_t off = 0;
    auto alloc = [&](size_t n) { float* r = ws + off; off += n; return r; };
    float* z      = alloc((size_t)PB * P4H);
    float* h      = alloc((size_t)PB * PH);
    float* c      = alloc((size_t)PB * PH);
    float* h0     = alloc((size_t)PB * PH);
    float* q      = alloc((size_t)PB * PH);
    float* catbuf = alloc((size_t)PB * 2 * PH);
    float* u_t    = alloc((size_t)PB * PS);
    float* a_buf  = alloc((size_t)PB * PS);
    float* cur    = alloc((size_t)PB * PD);

    init_kernel<<<1024, 256, 0, stream>>>(h, c, cur);
    for (int s = 0; s < PS; ++s) {
        gemm_nt<CF32, CF32, 64, 64, 32, 4, 4><<<dim3(P4H / 64, PB / 64), 256, 0, stream>>>(
            h, in.enc_Whh, nullptr, z, PB, P4H, PH);
        lstm_cell<CBF16><<<1024, 256, 0, stream>>>(
            z, in.inp + s * PD, PS * PD, in.enc_Wih, in.enc_bih, in.enc_bhh,
            c, h, enc_out + (size_t)s * PB * PH, PH);
    }
    gemm_nt<CBF16, CBF16, 64, 64, 32, 4, 4><<<dim3(PH / 64, (PS * PB) / 64), 256, 0, stream>>>(
        enc_out, in.W1, in.b1, W1e, PS * PB, PH, PH);
    for (int t = 0; t < PS; ++t) {
        gemm_nt<CF32, CF32, 64, 64, 32, 4, 4><<<dim3(P4H / 64, PB / 64), 256, 0, stream>>>(
            h, in.dec_Whh, nullptr, z, PB, P4H, PH);
        lstm_cell<CF32><<<1024, 256, 0, stream>>>(
            z, cur, PD, in.dec_Wih, in.dec_bih, in.dec_bhh,
            c, h0, catbuf + PH, 2 * PH);
        gemm_nt<CF32, CF32, 32, 32, 32, 2, 2><<<dim3(PH / 32, PB / 32), 256, 0, stream>>>(
            h0, in.W2, in.b2, q, PB, PH, PH);
        u_pass<CBF16><<<(PS * PB) / 4, 256, 0, stream>>>(W1e, q, in.v_w, in.v_b, u_t);
        softmax_step<<<PB / 4, 256, 0, stream>>>(u_t, in.inp, a_buf, out, cur, t);
        ctx_kernel<CBF16><<<PB, 256, 0, stream>>>(enc_out, a_buf, catbuf);
        gemm_nt<CF32, CF32, 32, 32, 32, 2, 2><<<dim3(PH / 32, PB / 32), 256, 0, stream>>>(
            catbuf, in.comb_W, in.comb_b, h, PB, PH, 2 * PH);
    }
}

extern "C" void kernel_launch(void* const* d_in, const int* in_sizes, int n_in,
                              void* d_out, int out_size, void* d_ws, size_t ws_size,
                              hipStream_t stream)
{
    Inputs in = unpack(d_in);
    float* out = (float*)d_out;

    // Tier-1 need (run_mfma2 layout, bytes):
    const size_t t1_need =
        BIG * 2 * 2 +                               // enc_out + W1e
        (size_t)P4H * PH * 2 * 4 +                  // whh_e + whh_d splits
        (size_t)PH * PH * 2 * 4 +                   // w1, w2 splits
        (size_t)(2 * PH) * PH * 2 * 2 +             // combT splits
        (size_t)P4H * (2 * PH) * 2 * 2 +            // W_fused splits
        (size_t)P4H * 2 * 4 * 2 +                   // wih perms
        (size_t)P4H * 4 * 3 +                       // bsums + b_fused
        (size_t)PB * PH * 4 * 3 +                   // hpp0, hpp1, cT
        (size_t)PB * 2 * PH * 4 * 2 +               // cat double buffer
        (size_t)PB * PD * 4;                        // cur
    const size_t t2_need =
        BIG * 2 * 2 +
        (size_t)P4H * PH * 2 * 4 +
        (size_t)PH * PH * 2 * 4 +
        (size_t)PH * 2 * PH * 2 * 2 +
        (size_t)P4H * 2 * 4 * 2 +
        (size_t)P4H * 4 * 2 +
        ((size_t)PB * PH * 6 + (size_t)PB * PS * 2 + PB * PD) * 4;
    const size_t t3_need =
        BIG * 2 * 2 +
        ((size_t)PB * P4H + 4 * (size_t)PB * PH + (size_t)PB * 2 * PH +
         2 * (size_t)PB * PS + (size_t)PB * PD) * 4;

    if (ws_size >= t1_need)       run_mfma2(in, out, d_ws, stream);
    else if (ws_size >= t2_need)  run_mfma(in, out, d_ws, stream);
    else if (ws_size >= t3_need)  run_fallback(in, out, d_ws, stream);
    // else: insufficient workspace — nothing safe to do.
}

// Round 7
// 10787.312 us; speedup vs baseline: 2.2448x; 1.0922x over previous
//
#include <hip/hip_runtime.h>

// Problem constants: B=512, S=128, D=2, H=512, 4H=2048
#define PB 512
#define PS 128
#define PD 2
#define PH 512
#define P4H 2048

typedef unsigned int u32;
typedef unsigned short u16;
typedef __attribute__((ext_vector_type(8))) short short8;
typedef __attribute__((ext_vector_type(4))) float f32x4;

__device__ __forceinline__ float fast_sigmoid(float x) {
    return __fdividef(1.0f, 1.0f + __expf(-x));
}
__device__ __forceinline__ float fast_tanh(float x) {
    float ax = fabsf(x);
    float e = __expf(-2.0f * ax);
    float r = __fdividef(1.0f - e, 1.0f + e);
    return x < 0.0f ? -r : r;
}

__device__ __forceinline__ float bf_dec_u(u16 v) { return __uint_as_float((u32)v << 16); }
__device__ __forceinline__ u16 bf_trunc(float v) { return (u16)(__float_as_uint(v) >> 16); }
__device__ __forceinline__ u16 bf_rne(float v) {
    u32 u = __float_as_uint(v);
    return (u16)((u + 0x7FFFu + ((u >> 16) & 1u)) >> 16);
}
// split: v ~= hi + lo, residual ~2^-17 relative
__device__ __forceinline__ void bf_split(float v, u16& hi, u16& lo) {
    hi = bf_trunc(v);
    lo = bf_rne(v - bf_dec_u(hi));
}

struct CF32 {
    using T = float;
    static __device__ __forceinline__ float dec(T v) { return v; }
    static __device__ __forceinline__ T enc(float v) { return v; }
    static __device__ __forceinline__ void dec4(const T* p, float* o) {
        float4 v = *(const float4*)p; o[0]=v.x; o[1]=v.y; o[2]=v.z; o[3]=v.w;
    }
};
struct CBF16 {
    using T = u16;
    static __device__ __forceinline__ float dec(T v) { return __uint_as_float((u32)v << 16); }
    static __device__ __forceinline__ T enc(float v) { return bf_rne(v); }
    static __device__ __forceinline__ void dec4(const T* p, float* o) {
        uint2 v = *(const uint2*)p;
        o[0] = __uint_as_float(v.x << 16);
        o[1] = __uint_as_float(v.x & 0xFFFF0000u);
        o[2] = __uint_as_float(v.y << 16);
        o[3] = __uint_as_float(v.y & 0xFFFF0000u);
    }
};

// ===========================================================================
// Prep kernels
// ===========================================================================
__global__ __launch_bounds__(256) void prep_whh(
    const float* __restrict__ Whh, u16* __restrict__ hi, u16* __restrict__ lo,
    float* __restrict__ f32out)
{
    int np = blockIdx.x;                 // 0..2047
    int j = np >> 2, g = np & 3;
    const float* src = Whh + (size_t)(g * PH + j) * PH;
    for (int k = threadIdx.x; k < PH; k += 256) {
        float v = src[k];
        u16 h_, l_;
        bf_split(v, h_, l_);
        hi[(size_t)np * PH + k] = h_;
        lo[(size_t)np * PH + k] = l_;
        if (f32out) f32out[(size_t)np * PH + k] = v;
    }
}
__global__ __launch_bounds__(256) void prep_split(
    const float* __restrict__ W, u16* __restrict__ hi, u16* __restrict__ lo, int K)
{
    int n = blockIdx.x;
    const float* src = W + (size_t)n * K;
    for (int k = threadIdx.x; k < K; k += 256) {
        u16 h_, l_;
        bf_split(src[k], h_, l_);
        hi[(size_t)n * K + k] = h_;
        lo[(size_t)n * K + k] = l_;
    }
}
// combT[m][k] = comb_W[k][m] (comb_W: [512][1024]) split to bf16 hi/lo.
__global__ __launch_bounds__(256) void prep_transpose_split(
    const float* __restrict__ W, u16* __restrict__ hi, u16* __restrict__ lo)
{
    __shared__ float tile[32][33];
    int m0 = blockIdx.x * 32;            // col base (0..1023)
    int k0 = blockIdx.y * 32;            // row base (0..511)
    int tx = threadIdx.x & 31, ty = threadIdx.x >> 5;   // ty 0..7
    #pragma unroll
    for (int i = 0; i < 4; ++i) {
        int k = k0 + ty + i * 8;
        tile[ty + i * 8][tx] = W[(size_t)k * (2 * PH) + m0 + tx];
    }
    __syncthreads();
    #pragma unroll
    for (int i = 0; i < 4; ++i) {
        int m = m0 + ty + i * 8;
        float v = tile[tx][ty + i * 8];
        u16 h_, l_; bf_split(v, h_, l_);
        hi[(size_t)m * PH + k0 + tx] = h_;
        lo[(size_t)m * PH + k0 + tx] = l_;
    }
}
__global__ __launch_bounds__(256) void prep_small(
    const float* __restrict__ Wih, const float* __restrict__ bih,
    const float* __restrict__ bhh, float* __restrict__ wihp, float* __restrict__ bs)
{
    int np = blockIdx.x * 256 + threadIdx.x;
    if (np >= P4H) return;
    int j = np >> 2, g = np & 3;
    int n = g * PH + j;
    wihp[np * 2]     = Wih[(size_t)n * PD];
    wihp[np * 2 + 1] = Wih[(size_t)n * PD + 1];
    bs[np] = bih[n] + bhh[n];
}
__global__ __launch_bounds__(256) void prep_bfused(
    const float* __restrict__ whh_f32p, const float* __restrict__ comb_b,
    const float* __restrict__ bsum_d, float* __restrict__ bf)
{
    int np = blockIdx.x * 4 + (threadIdx.x >> 6);
    int lane = threadIdx.x & 63;
    const float* wr = whh_f32p + (size_t)np * PH + lane * 8;
    const float* cb = comb_b + lane * 8;
    float s = 0.0f;
    #pragma unroll
    for (int i = 0; i < 8; ++i) s += wr[i] * cb[i];
    #pragma unroll
    for (int off = 32; off; off >>= 1) s += __shfl_xor(s, off);
    if (lane == 0) bf[np] = s + bsum_d[np];
}

// ===========================================================================
// lstm_fused32: 32 n' x 64 b tiles, grid (P4H/32, PB/64) = 512 blocks
// (2 blocks/CU). grid.x = n'-tile so consecutive blocks share the act panel
// and each XCD's L2 keeps ~1/8 of the weights.
// EXTRA_MODE: 0 none, 1 bf16 h copy, 2 fp32 h copy (extra[b*ex_stride+col]).
// ===========================================================================
template<int EXTRA_MODE, int KK>
__global__ __launch_bounds__(256, 2) void lstm_fused32(
    const u16* __restrict__ Whh_hi, const u16* __restrict__ Whh_lo,
    const float* __restrict__ wih_perm, const float* __restrict__ bsum,
    const float* __restrict__ x, int x_stride,
    const float* __restrict__ h_in,    // [b][KK]
    float* __restrict__ cT,            // [j][b]
    float* __restrict__ h_out,         // [b][512]
    void* __restrict__ extra, int ex_stride)
{
    __shared__ u16 As_hi[32][72];
    __shared__ u16 As_lo[32][72];
    __shared__ u16 Bs_hi[64][72];
    __shared__ u16 Bs_lo[64][72];

    const int tid = threadIdx.x;
    const int bnp = blockIdx.x * 32;    // n' base
    const int bb  = blockIdx.y * 64;    // b base
    const int w = tid >> 6;
    const int wm = w >> 1, wn = w & 1;  // wm: n'-half (16 rows), wn: b-half (32)
    const int lane = tid & 63;
    const int l15 = lane & 15, lq = lane >> 4;

    f32x4 acc0 = (f32x4)0.0f, acc1 = (f32x4)0.0f;

    for (int k0 = 0; k0 < KK; k0 += 64) {
        {   // stage A: 32 rows x 64 k, hi+lo (256 chunks of 16B each array)
            int row = tid >> 3, kc = (tid & 7) * 8;
            *(uint4*)&As_hi[row][kc] = *(const uint4*)&Whh_hi[(size_t)(bnp + row) * KK + k0 + kc];
            *(uint4*)&As_lo[row][kc] = *(const uint4*)&Whh_lo[(size_t)(bnp + row) * KK + k0 + kc];
        }
        #pragma unroll
        for (int rep = 0; rep < 4; ++rep) {   // stage B: 64 rows fp32 -> split
            int chunk = tid + rep * 256;
            int row = chunk >> 4, kc = (chunk & 15) * 4;
            float4 v = *(const float4*)&h_in[(size_t)(bb + row) * KK + k0 + kc];
            u16 h0_, l0_, h1_, l1_, h2_, l2_, h3_, l3_;
            bf_split(v.x, h0_, l0_); bf_split(v.y, h1_, l1_);
            bf_split(v.z, h2_, l2_); bf_split(v.w, h3_, l3_);
            *(uint2*)&Bs_hi[row][kc] = make_uint2((u32)h0_ | ((u32)h1_ << 16),
                                                  (u32)h2_ | ((u32)h3_ << 16));
            *(uint2*)&Bs_lo[row][kc] = make_uint2((u32)l0_ | ((u32)l1_ << 16),
                                                  (u32)l2_ | ((u32)l3_ << 16));
        }
        __syncthreads();
        #pragma unroll
        for (int ks = 0; ks < 2; ++ks) {
            int kk = ks * 32 + lq * 8;
            short8 ah, al, bh0, bl0, bh1, bl1;
            {
                int r = wm * 16 + l15;
                ah = *(const short8*)&As_hi[r][kk];
                al = *(const short8*)&As_lo[r][kk];
            }
            {
                int r = wn * 32 + l15;
                bh0 = *(const short8*)&Bs_hi[r][kk];
                bl0 = *(const short8*)&Bs_lo[r][kk];
                bh1 = *(const short8*)&Bs_hi[r + 16][kk];
                bl1 = *(const short8*)&Bs_lo[r + 16][kk];
            }
            acc0 = __builtin_amdgcn_mfma_f32_16x16x32_bf16(ah, bh0, acc0, 0, 0, 0);
            acc0 = __builtin_amdgcn_mfma_f32_16x16x32_bf16(ah, bl0, acc0, 0, 0, 0);
            acc0 = __builtin_amdgcn_mfma_f32_16x16x32_bf16(al, bh0, acc0, 0, 0, 0);
            acc1 = __builtin_amdgcn_mfma_f32_16x16x32_bf16(ah, bh1, acc1, 0, 0, 0);
            acc1 = __builtin_amdgcn_mfma_f32_16x16x32_bf16(ah, bl1, acc1, 0, 0, 0);
            acc1 = __builtin_amdgcn_mfma_f32_16x16x32_bf16(al, bh1, acc1, 0, 0, 0);
        }
        __syncthreads();
    }

    // Epilogue: lane-local LSTM cell; h transposed via LDS (8 j x 64 b).
    float* Hs = (float*)&As_hi[0][0];   // 8*66*4 = 2112 B < 4608 B
    const int np_loc = wm * 16 + lq * 4;
    const int np = bnp + np_loc;
    const float4 b4 = *(const float4*)&bsum[np];
    const float4 wA = *(const float4*)&wih_perm[np * 2];
    const float4 wB = *(const float4*)&wih_perm[np * 2 + 4];
    const int jg = np >> 2;
    #pragma unroll
    for (int nf = 0; nf < 2; ++nf) {
        int b_loc = wn * 32 + nf * 16 + l15;
        int b = bb + b_loc;
        float x0 = x[b * x_stride];
        float x1 = x[b * x_stride + 1];
        f32x4 a = nf ? acc1 : acc0;
        float zi = a[0] + b4.x + x0 * wA.x + x1 * wA.y;
        float zf = a[1] + b4.y + x0 * wA.z + x1 * wA.w;
        float zg = a[2] + b4.z + x0 * wB.x + x1 * wB.y;
        float zo = a[3] + b4.w + x0 * wB.z + x1 * wB.w;
        float cold = cT[(size_t)jg * PB + b];
        float cv = fast_sigmoid(zf) * cold + fast_sigmoid(zi) * fast_tanh(zg);
        float hv = fast_sigmoid(zo) * fast_tanh(cv);
        cT[(size_t)jg * PB + b] = cv;
        Hs[(np_loc >> 2) * 66 + b_loc] = hv;
    }
    __syncthreads();
    {
        int b_loc = tid & 63, jp = (tid >> 6) * 2;   // jp in {0,2,4,6}
        int b = bb + b_loc;
        int jbase = bnp >> 2;                        // blockIdx.x * 8
        float h0v = Hs[jp * 66 + b_loc];
        float h1v = Hs[(jp + 1) * 66 + b_loc];
        *(float2*)&h_out[(size_t)b * PH + jbase + jp] = make_float2(h0v, h1v);
        if (EXTRA_MODE == 1) {
            u16* e = (u16*)extra;
            *(u32*)&e[(size_t)b * ex_stride + jbase + jp] =
                (u32)bf_rne(h0v) | ((u32)bf_rne(h1v) << 16);
        } else if (EXTRA_MODE == 2) {
            float* e = (float*)extra;
            *(float2*)&e[(size_t)b * ex_stride + jbase + jp] = make_float2(h0v, h1v);
        }
    }
}

// ===========================================================================
// gemm32_f32: 32x32 tiles for the q-GEMM (grid 256 = 1/CU vs old 64 blocks).
// out[m][n] = act[m,:] . W[n,:] + bias[n], fp32 out.
// ===========================================================================
__global__ __launch_bounds__(256, 2) void gemm32_f32(
    const u16* __restrict__ Whi, const u16* __restrict__ Wlo,
    const float* __restrict__ act, const float* __restrict__ bias,
    float* __restrict__ out, int K, int ldo)
{
    __shared__ u16 As_hi[32][72];
    __shared__ u16 As_lo[32][72];
    __shared__ u16 Bs_hi[32][72];
    __shared__ u16 Bs_lo[32][72];

    const int tid = threadIdx.x;
    const int bn = blockIdx.x * 32;   // weight rows
    const int bm = blockIdx.y * 32;   // act rows
    const int w = tid >> 6;
    const int wm = w >> 1, wn = w & 1;
    const int lane = tid & 63, l15 = lane & 15, lq = lane >> 4;

    f32x4 acc = (f32x4)0.0f;

    for (int k0 = 0; k0 < K; k0 += 64) {
        {
            int row = tid >> 3, kc = (tid & 7) * 8;
            *(uint4*)&As_hi[row][kc] = *(const uint4*)&Whi[(size_t)(bn + row) * K + k0 + kc];
            *(uint4*)&As_lo[row][kc] = *(const uint4*)&Wlo[(size_t)(bn + row) * K + k0 + kc];
        }
        #pragma unroll
        for (int rep = 0; rep < 2; ++rep) {
            int chunk = tid + rep * 256;
            int row = chunk >> 4, kc = (chunk & 15) * 4;
            float4 v = *(const float4*)&act[(size_t)(bm + row) * K + k0 + kc];
            u16 h0_, l0_, h1_, l1_, h2_, l2_, h3_, l3_;
            bf_split(v.x, h0_, l0_); bf_split(v.y, h1_, l1_);
            bf_split(v.z, h2_, l2_); bf_split(v.w, h3_, l3_);
            *(uint2*)&Bs_hi[row][kc] = make_uint2((u32)h0_ | ((u32)h1_ << 16),
                                                  (u32)h2_ | ((u32)h3_ << 16));
            *(uint2*)&Bs_lo[row][kc] = make_uint2((u32)l0_ | ((u32)l1_ << 16),
                                                  (u32)l2_ | ((u32)l3_ << 16));
        }
        __syncthreads();
        #pragma unroll
        for (int ks = 0; ks < 2; ++ks) {
            int kk = ks * 32 + lq * 8;
            short8 ah = *(const short8*)&As_hi[wm * 16 + l15][kk];
            short8 al = *(const short8*)&As_lo[wm * 16 + l15][kk];
            short8 bh = *(const short8*)&Bs_hi[wn * 16 + l15][kk];
            short8 bl = *(const short8*)&Bs_lo[wn * 16 + l15][kk];
            acc = __builtin_amdgcn_mfma_f32_16x16x32_bf16(ah, bh, acc, 0, 0, 0);
            acc = __builtin_amdgcn_mfma_f32_16x16x32_bf16(ah, bl, acc, 0, 0, 0);
            acc = __builtin_amdgcn_mfma_f32_16x16x32_bf16(al, bh, acc, 0, 0, 0);
        }
        __syncthreads();
    }

    int m = bm + wn * 16 + l15;
    int n = bn + wm * 16 + lq * 4;
    float4 b4 = bias ? *(const float4*)&bias[n] : make_float4(0.f, 0.f, 0.f, 0.f);
    *(float4*)&out[(size_t)m * ldo + n] =
        make_float4(acc[0] + b4.x, acc[1] + b4.y, acc[2] + b4.z, acc[3] + b4.w);
}

// ===========================================================================
// lstm_fused (64x64, tier-2 verified) — unchanged
// ===========================================================================
template<int EXTRA_MODE, int KK>
__global__ __launch_bounds__(256) void lstm_fused(
    const u16* __restrict__ Whh_hi, const u16* __restrict__ Whh_lo,
    const float* __restrict__ wih_perm, const float* __restrict__ bsum,
    const float* __restrict__ x, int x_stride,
    const float* __restrict__ h_in,
    float* __restrict__ cT,
    float* __restrict__ h_out,
    void* __restrict__ extra, int ex_stride)
{
    __shared__ u16 As_hi[64][72];
    __shared__ u16 As_lo[64][72];
    __shared__ u16 Bs_hi[64][72];
    __shared__ u16 Bs_lo[64][72];

    const int tid = threadIdx.x;
    const int bb = blockIdx.x * 64;
    const int bn = blockIdx.y * 64;
    const int w = tid >> 6;
    const int wm = w >> 1, wn = w & 1;
    const int lane = tid & 63;
    const int l15 = lane & 15, lq = lane >> 4;

    f32x4 acc[2][2];
    #pragma unroll
    for (int i = 0; i < 2; ++i)
        #pragma unroll
        for (int j = 0; j < 2; ++j)
            acc[i][j] = (f32x4)0.0f;

    for (int k0 = 0; k0 < KK; k0 += 64) {
        #pragma unroll
        for (int rep = 0; rep < 2; ++rep) {
            int chunk = tid + rep * 256;
            int row = chunk >> 3, kc = (chunk & 7) * 8;
            *(uint4*)&As_hi[row][kc] = *(const uint4*)&Whh_hi[(size_t)(bn + row) * KK + k0 + kc];
            *(uint4*)&As_lo[row][kc] = *(const uint4*)&Whh_lo[(size_t)(bn + row) * KK + k0 + kc];
        }
        #pragma unroll
        for (int rep = 0; rep < 4; ++rep) {
            int chunk = tid + rep * 256;
            int row = chunk >> 4, kc = (chunk & 15) * 4;
            float4 v = *(const float4*)&h_in[(size_t)(bb + row) * KK + k0 + kc];
            u16 h0_, l0_, h1_, l1_, h2_, l2_, h3_, l3_;
            bf_split(v.x, h0_, l0_); bf_split(v.y, h1_, l1_);
            bf_split(v.z, h2_, l2_); bf_split(v.w, h3_, l3_);
            *(uint2*)&Bs_hi[row][kc] = make_uint2((u32)h0_ | ((u32)h1_ << 16),
                                                  (u32)h2_ | ((u32)h3_ << 16));
            *(uint2*)&Bs_lo[row][kc] = make_uint2((u32)l0_ | ((u32)l1_ << 16),
                                                  (u32)l2_ | ((u32)l3_ << 16));
        }
        __syncthreads();
        #pragma unroll
        for (int ks = 0; ks < 2; ++ks) {
            int kk = ks * 32 + lq * 8;
            short8 ah[2], al[2], bh[2], bl[2];
            #pragma unroll
            for (int mf = 0; mf < 2; ++mf) {
                int r = wm * 32 + mf * 16 + l15;
                ah[mf] = *(const short8*)&As_hi[r][kk];
                al[mf] = *(const short8*)&As_lo[r][kk];
            }
            #pragma unroll
            for (int nf = 0; nf < 2; ++nf) {
                int r = wn * 32 + nf * 16 + l15;
                bh[nf] = *(const short8*)&Bs_hi[r][kk];
                bl[nf] = *(const short8*)&Bs_lo[r][kk];
            }
            #pragma unroll
            for (int mf = 0; mf < 2; ++mf)
                #pragma unroll
                for (int nf = 0; nf < 2; ++nf) {
                    acc[mf][nf] = __builtin_amdgcn_mfma_f32_16x16x32_bf16(ah[mf], bh[nf], acc[mf][nf], 0, 0, 0);
                    acc[mf][nf] = __builtin_amdgcn_mfma_f32_16x16x32_bf16(ah[mf], bl[nf], acc[mf][nf], 0, 0, 0);
                    acc[mf][nf] = __builtin_amdgcn_mfma_f32_16x16x32_bf16(al[mf], bh[nf], acc[mf][nf], 0, 0, 0);
                }
        }
        __syncthreads();
    }

    float* Hs = (float*)&As_hi[0][0];
    #pragma unroll
    for (int nf = 0; nf < 2; ++nf) {
        int b_loc = wn * 32 + nf * 16 + l15;
        int b = bb + b_loc;
        float x0 = x[b * x_stride];
        float x1 = x[b * x_stride + 1];
        #pragma unroll
        for (int mf = 0; mf < 2; ++mf) {
            int np_loc = wm * 32 + mf * 16 + lq * 4;
            int np = bn + np_loc;
            float4 b4 = *(const float4*)&bsum[np];
            float4 wA = *(const float4*)&wih_perm[np * 2];
            float4 wB = *(const float4*)&wih_perm[np * 2 + 4];
            float zi = acc[mf][nf][0] + b4.x + x0 * wA.x + x1 * wA.y;
            float zf = acc[mf][nf][1] + b4.y + x0 * wA.z + x1 * wA.w;
            float zg = acc[mf][nf][2] + b4.z + x0 * wB.x + x1 * wB.y;
            float zo = acc[mf][nf][3] + b4.w + x0 * wB.z + x1 * wB.w;
            int jg = np >> 2;
            float cold = cT[(size_t)jg * PB + b];
            float cv = fast_sigmoid(zf) * cold + fast_sigmoid(zi) * fast_tanh(zg);
            float hv = fast_sigmoid(zo) * fast_tanh(cv);
            cT[(size_t)jg * PB + b] = cv;
            Hs[(np_loc >> 2) * 66 + b_loc] = hv;
        }
    }
    __syncthreads();
    {
        int b_loc = tid >> 2, jp = (tid & 3) * 4;
        int b = bb + b_loc;
        int jbase = bn >> 2;
        float4 hv4;
        hv4.x = Hs[(jp + 0) * 66 + b_loc];
        hv4.y = Hs[(jp + 1) * 66 + b_loc];
        hv4.z = Hs[(jp + 2) * 66 + b_loc];
        hv4.w = Hs[(jp + 3) * 66 + b_loc];
        *(float4*)&h_out[(size_t)b * PH + jbase + jp] = hv4;
        if (EXTRA_MODE == 1) {
            u16* e = (u16*)extra;
            *(uint2*)&e[(size_t)b * ex_stride + jbase + jp] =
                make_uint2((u32)bf_rne(hv4.x) | ((u32)bf_rne(hv4.y) << 16),
                           (u32)bf_rne(hv4.z) | ((u32)bf_rne(hv4.w) << 16));
        } else if (EXTRA_MODE == 2) {
            float* e = (float*)extra;
            *(float4*)&e[(size_t)b * ex_stride + jbase + jp] = hv4;
        }
    }
}

// ===========================================================================
// gemm_wtA (64x64) — unchanged, used for W1e / W_fused prep / tier-2
// ===========================================================================
template<int ACT_F32, int OUTMODE>
__global__ __launch_bounds__(256) void gemm_wtA(
    const u16* __restrict__ Whi, const u16* __restrict__ Wlo,
    const void* __restrict__ act, const float* __restrict__ bias,
    void* __restrict__ out, void* __restrict__ out2, int K, int ldo)
{
    __shared__ u16 As_hi[64][72];
    __shared__ u16 As_lo[64][72];
    __shared__ u16 Bs_hi[64][72];
    __shared__ u16 Bs_lo[64][72];

    const int tid = threadIdx.x;
    const int bm = blockIdx.x * 64;
    const int bn = blockIdx.y * 64;
    const int w = tid >> 6;
    const int wm = w >> 1, wn = w & 1;
    const int lane = tid & 63;
    const int l15 = lane & 15, lq = lane >> 4;

    f32x4 acc[2][2];
    #pragma unroll
    for (int i = 0; i < 2; ++i)
        #pragma unroll
        for (int j = 0; j < 2; ++j)
            acc[i][j] = (f32x4)0.0f;

    for (int k0 = 0; k0 < K; k0 += 64) {
        #pragma unroll
        for (int rep = 0; rep < 2; ++rep) {
            int chunk = tid + rep * 256;
            int row = chunk >> 3, kc = (chunk & 7) * 8;
            *(uint4*)&As_hi[row][kc] = *(const uint4*)&Whi[(size_t)(bn + row) * K + k0 + kc];
            *(uint4*)&As_lo[row][kc] = *(const uint4*)&Wlo[(size_t)(bn + row) * K + k0 + kc];
        }
        if (ACT_F32) {
            const float* a = (const float*)act;
            #pragma unroll
            for (int rep = 0; rep < 4; ++rep) {
                int chunk = tid + rep * 256;
                int row = chunk >> 4, kc = (chunk & 15) * 4;
                float4 v = *(const float4*)&a[(size_t)(bm + row) * K + k0 + kc];
                u16 h0_, l0_, h1_, l1_, h2_, l2_, h3_, l3_;
                bf_split(v.x, h0_, l0_); bf_split(v.y, h1_, l1_);
                bf_split(v.z, h2_, l2_); bf_split(v.w, h3_, l3_);
                *(uint2*)&Bs_hi[row][kc] = make_uint2((u32)h0_ | ((u32)h1_ << 16),
                                                      (u32)h2_ | ((u32)h3_ << 16));
                *(uint2*)&Bs_lo[row][kc] = make_uint2((u32)l0_ | ((u32)l1_ << 16),
                                                      (u32)l2_ | ((u32)l3_ << 16));
            }
        } else {
            const u16* a = (const u16*)act;
            #pragma unroll
            for (int rep = 0; rep < 2; ++rep) {
                int chunk = tid + rep * 256;
                int row = chunk >> 3, kc = (chunk & 7) * 8;
                *(uint4*)&Bs_hi[row][kc] = *(const uint4*)&a[(size_t)(bm + row) * K + k0 + kc];
            }
        }
        __syncthreads();
        #pragma unroll
        for (int ks = 0; ks < 2; ++ks) {
            int kk = ks * 32 + lq * 8;
            short8 ah[2], al[2], bh[2], bl[2];
            #pragma unroll
            for (int mf = 0; mf < 2; ++mf) {
                int r = wm * 32 + mf * 16 + l15;
                ah[mf] = *(const short8*)&As_hi[r][kk];
                al[mf] = *(const short8*)&As_lo[r][kk];
            }
            #pragma unroll
            for (int nf = 0; nf < 2; ++nf) {
                int r = wn * 32 + nf * 16 + l15;
                bh[nf] = *(const short8*)&Bs_hi[r][kk];
                if (ACT_F32) bl[nf] = *(const short8*)&Bs_lo[r][kk];
            }
            #pragma unroll
            for (int mf = 0; mf < 2; ++mf)
                #pragma unroll
                for (int nf = 0; nf < 2; ++nf) {
                    acc[mf][nf] = __builtin_amdgcn_mfma_f32_16x16x32_bf16(ah[mf], bh[nf], acc[mf][nf], 0, 0, 0);
                    if (ACT_F32) {
                        acc[mf][nf] = __builtin_amdgcn_mfma_f32_16x16x32_bf16(ah[mf], bl[nf], acc[mf][nf], 0, 0, 0);
                        acc[mf][nf] = __builtin_amdgcn_mfma_f32_16x16x32_bf16(al[mf], bh[nf], acc[mf][nf], 0, 0, 0);
                    } else {
                        acc[mf][nf] = __builtin_amdgcn_mfma_f32_16x16x32_bf16(al[mf], bh[nf], acc[mf][nf], 0, 0, 0);
                    }
                }
        }
        __syncthreads();
    }

    #pragma unroll
    for (int nf = 0; nf < 2; ++nf) {
        int m = bm + wn * 32 + nf * 16 + l15;
        #pragma unroll
        for (int mf = 0; mf < 2; ++mf) {
            int n = bn + wm * 32 + mf * 16 + lq * 4;
            float4 b4 = bias ? *(const float4*)&bias[n] : make_float4(0.f, 0.f, 0.f, 0.f);
            float v0 = acc[mf][nf][0] + b4.x;
            float v1 = acc[mf][nf][1] + b4.y;
            float v2 = acc[mf][nf][2] + b4.z;
            float v3 = acc[mf][nf][3] + b4.w;
            if (OUTMODE == 1) {
                u16* o = (u16*)out;
                *(uint2*)&o[(size_t)m * ldo + n] =
                    make_uint2((u32)bf_rne(v0) | ((u32)bf_rne(v1) << 16),
                               (u32)bf_rne(v2) | ((u32)bf_rne(v3) << 16));
            } else if (OUTMODE == 2) {
                u16 h0_, l0_, h1_, l1_, h2_, l2_, h3_, l3_;
                bf_split(v0, h0_, l0_); bf_split(v1, h1_, l1_);
                bf_split(v2, h2_, l2_); bf_split(v3, h3_, l3_);
                u16* oh = (u16*)out;
                u16* ol = (u16*)out2;
                *(uint2*)&oh[(size_t)m * ldo + n] =
                    make_uint2((u32)h0_ | ((u32)h1_ << 16), (u32)h2_ | ((u32)h3_ << 16));
                *(uint2*)&ol[(size_t)m * ldo + n] =
                    make_uint2((u32)l0_ | ((u32)l1_ << 16), (u32)l2_ | ((u32)l3_ << 16));
            } else {
                float* o = (float*)out;
                *(float4*)&o[(size_t)m * ldo + n] = make_float4(v0, v1, v2, v3);
            }
        }
    }
}

// ===========================================================================
// Fused attention step (tier-1, verified R6)
// ===========================================================================
__global__ __launch_bounds__(256) void attn_fused(
    const u16* __restrict__ W1e,      // [b][s][h] bf16
    const u16* __restrict__ enc_out,  // [b][s][h] bf16
    const float* __restrict__ qv,     // [b][512]
    const float* __restrict__ v_w, const float* __restrict__ v_b,
    const float* __restrict__ inp,
    float* __restrict__ out,
    float* __restrict__ cat_out,      // [b][1024] (left half written)
    float* __restrict__ cur, int t)
{
    __shared__ float u_s[PS];
    __shared__ float a_s[PS];
    const int b = blockIdx.x;
    const int tid = threadIdx.x;
    const int w = tid >> 6, lane = tid & 63;

    float q8[8], v8[8];
    {
        const float* qr = qv + (size_t)b * PH + lane * 8;
        CF32::dec4(qr, q8); CF32::dec4(qr + 4, q8 + 4);
        const float* vr = v_w + lane * 8;
        CF32::dec4(vr, v8); CF32::dec4(vr + 4, v8 + 4);
    }
    const float vb = v_b[0];
    const u16* wbase = W1e + (size_t)b * PS * PH + lane * 8;
    #pragma unroll 2
    for (int i = 0; i < 32; ++i) {
        int s = w * 32 + i;
        const u16* row = wbase + (size_t)s * PH;
        float w8[8];
        CBF16::dec4(row, w8); CBF16::dec4(row + 4, w8 + 4);
        float sum = 0.0f;
        #pragma unroll
        for (int j = 0; j < 8; ++j) sum += v8[j] * fast_tanh(w8[j] + q8[j]);
        #pragma unroll
        for (int off = 32; off; off >>= 1) sum += __shfl_xor(sum, off);
        if (lane == 0) u_s[s] = sum + vb;
    }
    __syncthreads();
    if (w == 0) {
        float2 uv = make_float2(u_s[lane * 2], u_s[lane * 2 + 1]);
        float m = fmaxf(uv.x, uv.y);
        int mi = (uv.y > uv.x) ? (lane * 2 + 1) : (lane * 2);
        #pragma unroll
        for (int off = 32; off; off >>= 1) {
            float om = __shfl_xor(m, off);
            int oi = __shfl_xor(mi, off);
            if (om > m || (om == m && oi < mi)) { m = om; mi = oi; }
        }
        float e0 = __expf(uv.x - m);
        float e1 = __expf(uv.y - m);
        float ssum = e0 + e1;
        #pragma unroll
        for (int off = 32; off; off >>= 1) ssum += __shfl_xor(ssum, off);
        float inv = __fdividef(1.0f, ssum);
        float2 av = make_float2(e0 * inv, e1 * inv);
        a_s[lane * 2] = av.x; a_s[lane * 2 + 1] = av.y;
        *(float2*)&out[(size_t)b * PS * PS + (size_t)t * PS + lane * 2] = av;
        if (lane == 0) {
            cur[b * 2]     = inp[(size_t)b * PS * PD + mi * PD];
            cur[b * 2 + 1] = inp[(size_t)b * PS * PD + mi * PD + 1];
        }
    }
    __syncthreads();
    float acc0 = 0.0f, acc1 = 0.0f;
    const u16* ebase = enc_out + (size_t)b * PS * PH + tid * 2;
    #pragma unroll 4
    for (int s = 0; s < PS; ++s) {
        float a = a_s[s];
        u32 pr = *(const u32*)(ebase + (size_t)s * PH);
        acc0 = fmaf(a, __uint_as_float(pr << 16), acc0);
        acc1 = fmaf(a, __uint_as_float(pr & 0xFFFF0000u), acc1);
    }
    *(float2*)&cat_out[(size_t)b * (2 * PH) + tid * 2] = make_float2(acc0, acc1);
}

// ===========================================================================
// Tier-2/3 kernels (verified fallbacks) — unchanged
// ===========================================================================
template<class C>
__global__ __launch_bounds__(256) void u_pass(
    const typename C::T* __restrict__ W1e, const float* __restrict__ q,
    const float* __restrict__ v_w, const float* __restrict__ v_b,
    float* __restrict__ u_t)
{
    int row = blockIdx.x * 4 + (threadIdx.x >> 6);
    int lane = threadIdx.x & 63;
    int s = row >> 9;
    int b = row & (PB - 1);
    const typename C::T* wr = W1e + (size_t)row * PH + lane * 8;
    const float* qr = q + (size_t)b * PH + lane * 8;
    const float* vr = v_w + lane * 8;
    float w8[8], q8[8], v8[8];
    C::dec4(wr, w8); C::dec4(wr + 4, w8 + 4);
    CF32::dec4(qr, q8); CF32::dec4(qr + 4, q8 + 4);
    CF32::dec4(vr, v8); CF32::dec4(vr + 4, v8 + 4);
    float sum = 0.0f;
    #pragma unroll
    for (int i = 0; i < 8; ++i)
        sum += v8[i] * fast_tanh(w8[i] + q8[i]);
    #pragma unroll
    for (int off = 32; off; off >>= 1) sum += __shfl_xor(sum, off);
    if (lane == 0) u_t[b * PS + s] = sum + v_b[0];
}

__global__ __launch_bounds__(256) void softmax_step(
    const float* __restrict__ u_t, const float* __restrict__ inp,
    float* __restrict__ a_buf, float* __restrict__ out,
    float* __restrict__ cur, int t)
{
    int b = blockIdx.x * 4 + (threadIdx.x >> 6);
    int lane = threadIdx.x & 63;
    float2 uv = *(const float2*)&u_t[b * PS + lane * 2];
    float m = fmaxf(uv.x, uv.y);
    int mi = (uv.y > uv.x) ? (lane * 2 + 1) : (lane * 2);
    #pragma unroll
    for (int off = 32; off; off >>= 1) {
        float om = __shfl_xor(m, off);
        int oi = __shfl_xor(mi, off);
        if (om > m || (om == m && oi < mi)) { m = om; mi = oi; }
    }
    float e0 = __expf(uv.x - m);
    float e1 = __expf(uv.y - m);
    float ssum = e0 + e1;
    #pragma unroll
    for (int off = 32; off; off >>= 1) ssum += __shfl_xor(ssum, off);
    float inv = __fdividef(1.0f, ssum);
    float2 av = make_float2(e0 * inv, e1 * inv);
    *(float2*)&a_buf[b * PS + lane * 2] = av;
    *(float2*)&out[(size_t)b * PS * PS + (size_t)t * PS + lane * 2] = av;
    if (lane == 0) {
        cur[b * 2]     = inp[(size_t)b * PS * PD + mi * PD];
        cur[b * 2 + 1] = inp[(size_t)b * PS * PD + mi * PD + 1];
    }
}

template<class C>
__global__ __launch_bounds__(256) void ctx_kernel(
    const typename C::T* __restrict__ enc_out, const float* __restrict__ a_buf,
    float* __restrict__ catbuf)
{
    int b = blockIdx.x;
    int hidx = threadIdx.x;
    const float* ab = a_buf + b * PS;
    const typename C::T* e = enc_out + (size_t)b * PH;
    float acc0 = 0.0f, acc1 = 0.0f;
    #pragma unroll 4
    for (int s = 0; s < PS; ++s) {
        float a = ab[s];
        const typename C::T* es = e + (size_t)s * PB * PH;
        acc0 = fmaf(a, C::dec(es[hidx]), acc0);
        acc1 = fmaf(a, C::dec(es[hidx + 256]), acc1);
    }
    catbuf[(size_t)b * (2 * PH) + hidx] = acc0;
    catbuf[(size_t)b * (2 * PH) + hidx + 256] = acc1;
}

__global__ __launch_bounds__(256) void init_kernel(
    float* __restrict__ h, float* __restrict__ c, float* __restrict__ cur)
{
    int i = blockIdx.x * 256 + threadIdx.x;
    if (i < PB * PH) { h[i] = 0.0f; c[i] = 0.0f; }
    if (i < PB * PD) cur[i] = -1.0f;
}

template<class CA, class CO, int BM, int BN, int BK, int TM, int TN>
__global__ __launch_bounds__(256) void gemm_nt(
    const typename CA::T* __restrict__ A, const float* __restrict__ Bm,
    const float* __restrict__ bias, typename CO::T* __restrict__ C,
    int M, int N, int K)
{
    __shared__ float As[BK][BM];
    __shared__ float Bs[BK][BN];
    constexpr int TCOLS = BN / TN;
    constexpr int TROWS = BM / TM;
    static_assert(TCOLS * TROWS == 256, "thread tiling");
    const int tid = threadIdx.x;
    const int tc = tid % TCOLS;
    const int tr = tid / TCOLS;
    const int bm = blockIdx.y * BM;
    const int bn = blockIdx.x * BN;
    constexpr int AF4 = BM * BK / 4;
    constexpr int BF4 = BN * BK / 4;
    constexpr int KQ  = BK / 4;
    float acc[TM][TN];
    #pragma unroll
    for (int m = 0; m < TM; ++m)
        #pragma unroll
        for (int n = 0; n < TN; ++n) acc[m][n] = 0.0f;
    for (int k0 = 0; k0 < K; k0 += BK) {
        #pragma unroll
        for (int i = tid; i < AF4; i += 256) {
            int r = i / KQ, kq = i % KQ;
            float v4[4];
            CA::dec4(A + (size_t)(bm + r) * K + k0 + kq * 4, v4);
            As[kq*4+0][r] = v4[0]; As[kq*4+1][r] = v4[1];
            As[kq*4+2][r] = v4[2]; As[kq*4+3][r] = v4[3];
        }
        #pragma unroll
        for (int i = tid; i < BF4; i += 256) {
            int r = i / KQ, kq = i % KQ;
            const float4 v = *(const float4*)(Bm + (size_t)(bn + r) * K + k0 + kq * 4);
            Bs[kq*4+0][r] = v.x; Bs[kq*4+1][r] = v.y;
            Bs[kq*4+2][r] = v.z; Bs[kq*4+3][r] = v.w;
        }
        __syncthreads();
        #pragma unroll
        for (int k = 0; k < BK; ++k) {
            float av[TM], bv[TN];
            #pragma unroll
            for (int m = 0; m < TM; ++m) av[m] = As[k][tr * TM + m];
            #pragma unroll
            for (int n = 0; n < TN; ++n) bv[n] = Bs[k][tc * TN + n];
            #pragma unroll
            for (int m = 0; m < TM; ++m)
                #pragma unroll
                for (int n = 0; n < TN; ++n)
                    acc[m][n] = fmaf(av[m], bv[n], acc[m][n]);
        }
        __syncthreads();
    }
    #pragma unroll
    for (int m = 0; m < TM; ++m) {
        int row = bm + tr * TM + m;
        #pragma unroll
        for (int n = 0; n < TN; ++n) {
            int col = bn + tc * TN + n;
            float v = acc[m][n];
            if (bias) v += bias[col];
            C[(size_t)row * N + col] = CO::enc(v);
        }
    }
}

template<class CE>
__global__ __launch_bounds__(256) void lstm_cell(
    const float* __restrict__ z,
    const float* __restrict__ x, int x_stride,
    const float* __restrict__ Wih,
    const float* __restrict__ bih, const float* __restrict__ bhh,
    float* __restrict__ c, float* __restrict__ h,
    typename CE::T* __restrict__ extra, int extra_stride)
{
    int idx = blockIdx.x * 256 + threadIdx.x;
    int b = idx >> 9, j = idx & (PH - 1);
    float x0 = x[b * x_stride];
    float x1 = x[b * x_stride + 1];
    const float* zr = z + (size_t)b * P4H;
    float zi = zr[j]        + bih[j]        + bhh[j]        + x0 * Wih[2*j]          + x1 * Wih[2*j+1];
    float zf = zr[j + PH]   + bih[j + PH]   + bhh[j + PH]   + x0 * Wih[2*(j+PH)]     + x1 * Wih[2*(j+PH)+1];
    float zg = zr[j + 2*PH] + bih[j + 2*PH] + bhh[j + 2*PH] + x0 * Wih[2*(j+2*PH)]   + x1 * Wih[2*(j+2*PH)+1];
    float zo = zr[j + 3*PH] + bih[j + 3*PH] + bhh[j + 3*PH] + x0 * Wih[2*(j+3*PH)]   + x1 * Wih[2*(j+3*PH)+1];
    float cv = fast_sigmoid(zf) * c[idx] + fast_sigmoid(zi) * fast_tanh(zg);
    float hv = fast_sigmoid(zo) * fast_tanh(cv);
    c[idx] = cv;
    h[idx] = hv;
    if (extra) extra[(size_t)b * extra_stride + j] = CE::enc(hv);
}

// ===========================================================================
// Drivers
// ===========================================================================
struct Inputs {
    const float *inp, *enc_Wih, *enc_Whh, *enc_bih, *enc_bhh;
    const float *dec_Wih, *dec_Whh, *dec_bih, *dec_bhh;
    const float *W1, *b1, *W2, *b2, *v_w, *v_b, *comb_W, *comb_b;
};
static Inputs unpack(void* const* d_in) {
    Inputs in;
    in.inp = (const float*)d_in[0];
    in.enc_Wih = (const float*)d_in[1]; in.enc_Whh = (const float*)d_in[2];
    in.enc_bih = (const float*)d_in[3]; in.enc_bhh = (const float*)d_in[4];
    in.dec_Wih = (const float*)d_in[5]; in.dec_Whh = (const float*)d_in[6];
    in.dec_bih = (const float*)d_in[7]; in.dec_bhh = (const float*)d_in[8];
    in.W1 = (const float*)d_in[9];  in.b1 = (const float*)d_in[10];
    in.W2 = (const float*)d_in[11]; in.b2 = (const float*)d_in[12];
    in.v_w = (const float*)d_in[13]; in.v_b = (const float*)d_in[14];
    in.comb_W = (const float*)d_in[15]; in.comb_b = (const float*)d_in[16];
    return in;
}

static const size_t BIG = (size_t)PS * PB * PH;   // 33,554,432 elems

// ---------------- Tier 1: squeezed workspace + 2-blocks/CU kernels ---------
// t1_need = 157,347,840 B  (< 162,058,240 B known-available from R4's tier)
static void run_mfma2(const Inputs& in, float* out, void* d_ws, hipStream_t stream)
{
    char* p = (char*)d_ws;
    auto alloc = [&](size_t bytes) { char* r = p; p += bytes; return r; };
    u16* enc_out  = (u16*)alloc(BIG * 2);                     // [b][s][h]
    char* W1e_reg = alloc(BIG * 2);                           // [b][s][h] (also hosts prep/encoder temporaries)
    u16* W1e = (u16*)W1e_reg;
    u16* whh_d_hi = (u16*)alloc((size_t)P4H * PH * 2);
    u16* whh_d_lo = (u16*)alloc((size_t)P4H * PH * 2);
    u16* w1h = (u16*)alloc((size_t)PH * PH * 2);
    u16* w1l = (u16*)alloc((size_t)PH * PH * 2);
    u16* w2h = (u16*)alloc((size_t)PH * PH * 2);
    u16* w2l = (u16*)alloc((size_t)PH * PH * 2);
    u16* wf_h = (u16*)alloc((size_t)P4H * (2 * PH) * 2);      // W_fused split
    u16* wf_l = (u16*)alloc((size_t)P4H * (2 * PH) * 2);
    float* wih_e = (float*)alloc((size_t)P4H * 2 * 4);
    float* wih_d = (float*)alloc((size_t)P4H * 2 * 4);
    float* bsum_e = (float*)alloc((size_t)P4H * 4);
    float* bsum_d = (float*)alloc((size_t)P4H * 4);
    float* b_fus  = (float*)alloc((size_t)P4H * 4);
    float* hpp0 = (float*)alloc((size_t)PB * PH * 4);
    float* cT   = (float*)alloc((size_t)PB * PH * 4);
    float* h0   = (float*)alloc((size_t)PB * PH * 4);
    float* q    = (float*)alloc((size_t)PB * PH * 4);
    float* catreg = (float*)alloc((size_t)PB * 2 * PH * 4 * 2);  // 2 cat buffers
    float* cur  = (float*)alloc((size_t)PB * PD * 4);

    // Aliases inside W1e region (all dead before the W1e GEMM writes it):
    //   [ctw_h 2.1M][ctw_l 2.1M][whh_e_hi 4.2M][whh_e_lo 4.2M][hpp1 1.05M]
    u16* ctw_h = (u16*)W1e_reg;
    u16* ctw_l = (u16*)(W1e_reg + 2097152);
    u16* whh_e_hi = (u16*)(W1e_reg + 2 * 2097152);
    u16* whh_e_lo = (u16*)(W1e_reg + 2 * 2097152 + 2097152);  // wrong? see below
    // careful: whh_e is P4H*PH*2 = 2,097,152 B each
    whh_e_hi = (u16*)(W1e_reg + 4194304);
    whh_e_lo = (u16*)(W1e_reg + 4194304 + 2097152);
    float* hpp1 = (float*)(W1e_reg + 4194304 + 2 * 2097152);
    // Alias: fp32 permuted dec-Whh over the cat region (prep-only lifetime;
    // cat[1] first written by attn at t=0, cat[0] at t=1 — both after prep).
    float* whh_f32p = catreg;
    float* cat[2] = { catreg, catreg + (size_t)PB * 2 * PH };
    float* hpp[2] = { hpp0, hpp1 };

    // ---- prep ----
    prep_whh<<<P4H, 256, 0, stream>>>(in.enc_Whh, whh_e_hi, whh_e_lo, nullptr);
    prep_whh<<<P4H, 256, 0, stream>>>(in.dec_Whh, whh_d_hi, whh_d_lo, whh_f32p);
    prep_split<<<PH, 256, 0, stream>>>(in.W1, w1h, w1l, PH);
    prep_split<<<PH, 256, 0, stream>>>(in.W2, w2h, w2l, PH);
    prep_transpose_split<<<dim3(32, 16), 256, 0, stream>>>(in.comb_W, ctw_h, ctw_l);
    prep_small<<<P4H / 256, 256, 0, stream>>>(in.enc_Wih, in.enc_bih, in.enc_bhh, wih_e, bsum_e);
    prep_small<<<P4H / 256, 256, 0, stream>>>(in.dec_Wih, in.dec_bih, in.dec_bhh, wih_d, bsum_d);
    gemm_wtA<1, 2><<<dim3(P4H / 64, (2 * PH) / 64), 256, 0, stream>>>(
        ctw_h, ctw_l, whh_f32p, nullptr, wf_h, wf_l, PH, 2 * PH);
    prep_bfused<<<P4H / 4, 256, 0, stream>>>(whh_f32p, in.comb_b, bsum_d, b_fus);
    init_kernel<<<1024, 256, 0, stream>>>(hpp0, cT, cur);

    // ---- encoder (lstm32: grid.x = n'-tile for XCD/L2 locality) ----
    for (int s = 0; s < PS; ++s) {
        lstm_fused32<1, PH><<<dim3(P4H / 32, PB / 64), 256, 0, stream>>>(
            whh_e_hi, whh_e_lo, wih_e, bsum_e,
            in.inp + s * PD, PS * PD,
            hpp[s & 1], cT, hpp[(s + 1) & 1],
            enc_out + (size_t)s * PH, PS * PH);
    }

    // ---- W1e = enc_out @ W1.T + b1 (overwrites the prep/encoder aliases) ----
    gemm_wtA<0, 1><<<dim3((PS * PB) / 64, PH / 64), 256, 0, stream>>>(
        w1h, w1l, enc_out, in.b1, W1e, nullptr, PH, PH);

    // ---- decoder: 3 kernels/step ----
    for (int t = 0; t < PS; ++t) {
        float* cat_out = cat[(t + 1) & 1];
        if (t == 0) {
            lstm_fused32<2, PH><<<dim3(P4H / 32, PB / 64), 256, 0, stream>>>(
                whh_d_hi, whh_d_lo, wih_d, bsum_d,
                cur, PD, hpp[0], cT, h0, cat_out + PH, 2 * PH);
        } else {
            lstm_fused32<2, 2 * PH><<<dim3(P4H / 32, PB / 64), 256, 0, stream>>>(
                wf_h, wf_l, wih_d, b_fus,
                cur, PD, cat[t & 1], cT, h0, cat_out + PH, 2 * PH);
        }
        gemm32_f32<<<dim3(PH / 32, PB / 32), 256, 0, stream>>>(
            w2h, w2l, h0, in.b2, q, PH, PH);
        attn_fused<<<PB, 256, 0, stream>>>(
            W1e, enc_out, q, in.v_w, in.v_b, in.inp, out, cat_out, cur, t);
    }
}

// ---------------- Tier 2: Round-4 verified MFMA path ----------------------
static void run_mfma(const Inputs& in, float* out, void* d_ws, hipStream_t stream)
{
    char* p = (char*)d_ws;
    auto alloc = [&](size_t bytes) { char* r = p; p += bytes; return r; };
    u16* enc_out = (u16*)alloc(BIG * 2);
    u16* W1e     = (u16*)alloc(BIG * 2);
    u16* whh_e_hi = (u16*)alloc((size_t)P4H * PH * 2);
    u16* whh_e_lo = (u16*)alloc((size_t)P4H * PH * 2);
    u16* whh_d_hi = (u16*)alloc((size_t)P4H * PH * 2);
    u16* whh_d_lo = (u16*)alloc((size_t)P4H * PH * 2);
    u16* w1h = (u16*)alloc((size_t)PH * PH * 2);
    u16* w1l = (u16*)alloc((size_t)PH * PH * 2);
    u16* w2h = (u16*)alloc((size_t)PH * PH * 2);
    u16* w2l = (u16*)alloc((size_t)PH * PH * 2);
    u16* cwh = (u16*)alloc((size_t)PH * 2 * PH * 2);
    u16* cwl = (u16*)alloc((size_t)PH * 2 * PH * 2);
    float* wih_e = (float*)alloc((size_t)P4H * 2 * 4);
    float* wih_d = (float*)alloc((size_t)P4H * 2 * 4);
    float* bsum_e = (float*)alloc((size_t)P4H * 4);
    float* bsum_d = (float*)alloc((size_t)P4H * 4);
    float* hpp0 = (float*)alloc((size_t)PB * PH * 4);
    float* hpp1 = (float*)alloc((size_t)PB * PH * 4);
    float* cT   = (float*)alloc((size_t)PB * PH * 4);
    float* h0   = (float*)alloc((size_t)PB * PH * 4);
    float* q    = (float*)alloc((size_t)PB * PH * 4);
    float* catbuf = (float*)alloc((size_t)PB * 2 * PH * 4);
    float* u_t  = (float*)alloc((size_t)PB * PS * 4);
    float* a_buf = (float*)alloc((size_t)PB * PS * 4);
    float* cur  = (float*)alloc((size_t)PB * PD * 4);
    float* hpp[2] = { hpp0, hpp1 };

    prep_whh<<<P4H, 256, 0, stream>>>(in.enc_Whh, whh_e_hi, whh_e_lo, nullptr);
    prep_whh<<<P4H, 256, 0, stream>>>(in.dec_Whh, whh_d_hi, whh_d_lo, nullptr);
    prep_split<<<PH, 256, 0, stream>>>(in.W1, w1h, w1l, PH);
    prep_split<<<PH, 256, 0, stream>>>(in.W2, w2h, w2l, PH);
    prep_split<<<PH, 256, 0, stream>>>(in.comb_W, cwh, cwl, 2 * PH);
    prep_small<<<P4H / 256, 256, 0, stream>>>(in.enc_Wih, in.enc_bih, in.enc_bhh, wih_e, bsum_e);
    prep_small<<<P4H / 256, 256, 0, stream>>>(in.dec_Wih, in.dec_bih, in.dec_bhh, wih_d, bsum_d);
    init_kernel<<<1024, 256, 0, stream>>>(hpp0, cT, cur);

    for (int s = 0; s < PS; ++s) {
        lstm_fused<1, PH><<<dim3(PB / 64, P4H / 64), 256, 0, stream>>>(
            whh_e_hi, whh_e_lo, wih_e, bsum_e,
            in.inp + s * PD, PS * PD,
            hpp[s & 1], cT, hpp[(s + 1) & 1],
            enc_out + (size_t)s * PB * PH, PH);
    }
    gemm_wtA<0, 1><<<dim3((PS * PB) / 64, PH / 64), 256, 0, stream>>>(
        w1h, w1l, enc_out, in.b1, W1e, nullptr, PH, PH);
    for (int t = 0; t < PS; ++t) {
        lstm_fused<2, PH><<<dim3(PB / 64, P4H / 64), 256, 0, stream>>>(
            whh_d_hi, whh_d_lo, wih_d, bsum_d,
            cur, PD, hpp[t & 1], cT, h0, catbuf + PH, 2 * PH);
        gemm_wtA<1, 0><<<dim3(PB / 64, PH / 64), 256, 0, stream>>>(
            w2h, w2l, h0, in.b2, q, nullptr, PH, PH);
        u_pass<CBF16><<<(PS * PB) / 4, 256, 0, stream>>>(W1e, q, in.v_w, in.v_b, u_t);
        softmax_step<<<PB / 4, 256, 0, stream>>>(u_t, in.inp, a_buf, out, cur, t);
        ctx_kernel<CBF16><<<PB, 256, 0, stream>>>(enc_out, a_buf, catbuf);
        gemm_wtA<1, 0><<<dim3(PB / 64, PH / 64), 256, 0, stream>>>(
            cwh, cwl, catbuf, in.comb_b, hpp[(t + 1) & 1], nullptr, 2 * PH, PH);
    }
}

// ---------------- Tier 3: vector-ALU fallback ------------------------------
static void run_fallback(const Inputs& in, float* out, void* d_ws, hipStream_t stream)
{
    char* p = (char*)d_ws;
    u16* enc_out = (u16*)p;  p += BIG * 2;
    u16* W1e     = (u16*)p;  p += BIG * 2;
    float* ws = (float*)p;
    size_t off = 0;
    auto alloc = [&](size_t n) { float* r = ws + off; off += n; return r; };
    float* z      = alloc((size_t)PB * P4H);
    float* h      = alloc((size_t)PB * PH);
    float* c      = alloc((size_t)PB * PH);
    float* h0     = alloc((size_t)PB * PH);
    float* q      = alloc((size_t)PB * PH);
    float* catbuf = alloc((size_t)PB * 2 * PH);
    float* u_t    = alloc((size_t)PB * PS);
    float* a_buf  = alloc((size_t)PB * PS);
    float* cur    = alloc((size_t)PB * PD);

    init_kernel<<<1024, 256, 0, stream>>>(h, c, cur);
    for (int s = 0; s < PS; ++s) {
        gemm_nt<CF32, CF32, 64, 64, 32, 4, 4><<<dim3(P4H / 64, PB / 64), 256, 0, stream>>>(
            h, in.enc_Whh, nullptr, z, PB, P4H, PH);
        lstm_cell<CBF16><<<1024, 256, 0, stream>>>(
            z, in.inp + s * PD, PS * PD, in.enc_Wih, in.enc_bih, in.enc_bhh,
            c, h, enc_out + (size_t)s * PB * PH, PH);
    }
    gemm_nt<CBF16, CBF16, 64, 64, 32, 4, 4><<<dim3(PH / 64, (PS * PB) / 64), 256, 0, stream>>>(
        enc_out, in.W1, in.b1, W1e, PS * PB, PH, PH);
    for (int t = 0; t < PS; ++t) {
        gemm_nt<CF32, CF32, 64, 64, 32, 4, 4><<<dim3(P4H / 64, PB / 64), 256, 0, stream>>>(
            h, in.dec_Whh, nullptr, z, PB, P4H, PH);
        lstm_cell<CF32><<<1024, 256, 0, stream>>>(
            z, cur, PD, in.dec_Wih, in.dec_bih, in.dec_bhh,
            c, h0, catbuf + PH, 2 * PH);
        gemm_nt<CF32, CF32, 32, 32, 32, 2, 2><<<dim3(PH / 32, PB / 32), 256, 0, stream>>>(
            h0, in.W2, in.b2, q, PB, PH, PH);
        u_pass<CBF16><<<(PS * PB) / 4, 256, 0, stream>>>(W1e, q, in.v_w, in.v_b, u_t);
        softmax_step<<<PB / 4, 256, 0, stream>>>(u_t, in.inp, a_buf, out, cur, t);
        ctx_kernel<CBF16><<<PB, 256, 0, stream>>>(enc_out, a_buf, catbuf);
        gemm_nt<CF32, CF32, 32, 32, 32, 2, 2><<<dim3(PH / 32, PB / 32), 256, 0, stream>>>(
            catbuf, in.comb_W, in.comb_b, h, PB, PH, 2 * PH);
    }
}

extern "C" void kernel_launch(void* const* d_in, const int* in_sizes, int n_in,
                              void* d_out, int out_size, void* d_ws, size_t ws_size,
                              hipStream_t stream)
{
    Inputs in = unpack(d_in);
    float* out = (float*)d_out;

    // Tier-1 need (exact, per run_mfma2 allocs): 157,347,840 bytes
    const size_t t1_need =
        BIG * 2 * 2 +                               // enc_out + W1e region
        (size_t)P4H * PH * 2 * 2 +                  // whh_d splits
        (size_t)PH * PH * 2 * 4 +                   // w1, w2 splits
        (size_t)P4H * (2 * PH) * 2 * 2 +            // W_fused splits
        (size_t)P4H * 2 * 4 * 2 +                   // wih perms
        (size_t)P4H * 4 * 3 +                       // bsums + b_fused
        (size_t)PB * PH * 4 * 4 +                   // hpp0, cT, h0, q
        (size_t)PB * 2 * PH * 4 * 2 +               // cat double buffer
        (size_t)PB * PD * 4;                        // cur
    const size_t t2_need =
        BIG * 2 * 2 +
        (size_t)P4H * PH * 2 * 4 +
        (size_t)PH * PH * 2 * 4 +
        (size_t)PH * 2 * PH * 2 * 2 +
        (size_t)P4H * 2 * 4 * 2 +
        (size_t)P4H * 4 * 2 +
        ((size_t)PB * PH * 6 + (size_t)PB * PS * 2 + PB * PD) * 4;
    const size_t t3_need =
        BIG * 2 * 2 +
        ((size_t)PB * P4H + 4 * (size_t)PB * PH + (size_t)PB * 2 * PH +
         2 * (size_t)PB * PS + (size_t)PB * PD) * 4;

    if (ws_size >= t1_need)       run_mfma2(in, out, d_ws, stream);
    else if (ws_size >= t2_need)  run_mfma(in, out, d_ws, stream);
    else if (ws_size >= t3_need)  run_fallback(in, out, d_ws, stream);
    // else: insufficient workspace — nothing safe to do.
}